// Round 8
// baseline (430.126 us; speedup 1.0000x reference)
//
#include <hip/hip_runtime.h>
#include <math.h>

#define LEVELS 16
#define TBL 524288          // 2^19 entries per level
#define TMASK (TBL - 1)

typedef short bf16x8 __attribute__((ext_vector_type(8)));
typedef float f32x4  __attribute__((ext_vector_type(4)));
typedef float fvec4  __attribute__((ext_vector_type(4)));
typedef unsigned int uvec4 __attribute__((ext_vector_type(4)));

static __device__ __forceinline__ unsigned short f2bf(float x) {
    unsigned u = __float_as_uint(x);
    u += 0x7fffu + ((u >> 16) & 1u);    // RNE
    return (unsigned short)(u >> 16);
}
static __device__ __forceinline__ float b2f(unsigned short h) {
    return __uint_as_float(((unsigned)h) << 16);
}

// SH degree-4 block, constants computed exactly as round-1 (verified correct).
#define SH_BLOCK(sh, dx, dy, dz)                                                          \
    const float x2 = dx * dx, y2 = dy * dy, z2 = dz * dz;                                 \
    const float xy = dx * dy, xz = dx * dz, yz = dy * dz;                                 \
    const float x4 = x2 * x2, y4 = y2 * y2;                                               \
    const float c0  = (float)(0.5 * sqrt(1.0 / M_PI));                                    \
    const float c1  = (float)(0.5 * sqrt(3.0 / M_PI));                                    \
    const float sub = (float)(0.25 * sqrt(5.0 / M_PI));                                   \
    const float v1  = (float)(0.25 * sqrt(15.0 / M_PI));                                  \
    const float v2  = (float)(0.5 * sqrt(15.0 / M_PI));                                   \
    const float v3  = (float)(0.75 * sqrt(5.0 / M_PI));                                   \
    const float w1c = (float)(0.25 * sqrt(105.0 / M_PI));                                 \
    const float w2c = (float)(0.5 * sqrt(105.0 / M_PI));                                  \
    const float w3c = (float)(0.25 * sqrt(35.0 / (2.0 * M_PI)));                          \
    const float w4c = (float)(0.5 * sqrt(7.0 / (6.0 * M_PI)));                            \
    sh[0] = c0;                                                                           \
    sh[1] = -c1 * dy;                                                                     \
    sh[2] =  c1 * dz;                                                                     \
    sh[3] = -c1 * dx;                                                                     \
    sh[4] =  v2 * xy;                                                                     \
    sh[5] = -v2 * yz;                                                                     \
    sh[6] =  v3 * z2 - sub;                                                               \
    sh[7] = -v2 * xz;                                                                     \
    sh[8] =  v1 * x2 - v1 * y2;                                                           \
    sh[9]  = -w3c * dy * (3.0f * x2 - y2);                                                \
    sh[10] =  w2c * xy * dz;                                                              \
    sh[11] =  w4c * dy * (1.5f - 7.5f * z2);                                              \
    sh[12] =  1.24392110863372f * dz * (1.5f * z2 - 0.5f) - 0.497568443453487f * dz;      \
    sh[13] =  w4c * dx * (1.5f - 7.5f * z2);                                              \
    sh[14] =  w1c * dz * (x2 - y2);                                                       \
    sh[15] = -w3c * dx * (x2 - 3.0f * y2);                                                \
    sh[16] =  2.5033429417967f * xy * (x2 - y2);                                          \
    sh[17] = -1.77013076977993f * yz * (3.0f * x2 - y2);                                  \
    sh[18] =  0.126156626101008f * xy * (52.5f * z2 - 7.5f);                              \
    sh[19] =  0.267618617422916f * dy * (2.33333333333333f * dz * (1.5f - 7.5f * z2) + 4.0f * dz); \
    sh[20] =  1.48099765681286f * dz * (1.66666666666667f * dz * (1.5f * z2 - 0.5f) - 0.666666666666667f * dz) \
              - 0.952069922236839f * z2 + 0.317356640745613f;                             \
    sh[21] =  0.267618617422916f * dx * (2.33333333333333f * dz * (1.5f - 7.5f * z2) + 4.0f * dz); \
    sh[22] =  0.063078313050504f * (x2 - y2) * (52.5f * z2 - 7.5f);                       \
    sh[23] = -1.77013076977993f * xz * (x2 - 3.0f * y2);                                  \
    sh[24] = -3.75501441269506f * x2 * y2 + 0.625835735449176f * x4 + 0.625835735449176f * y4;

// ------------------------------------------------------------------
// Kernel 0: pack fp32 tables -> bf16x2 (one uint per entry).
// ------------------------------------------------------------------
__global__ __launch_bounds__(256)
void cvt_tables(const float* __restrict__ tables,
                unsigned int* __restrict__ tb16, int total)
{
    const int i = (blockIdx.x * 256 + threadIdx.x) * 4;   // 4 entries/thread
    if (i >= total) return;
    const fvec4 a = __builtin_nontemporal_load((const fvec4*)(tables + 2 * (size_t)i));
    const fvec4 b = __builtin_nontemporal_load((const fvec4*)(tables + 2 * (size_t)i) + 1);
    uvec4 o;
    o.x = ((unsigned)f2bf(a.y) << 16) | f2bf(a.x);
    o.y = ((unsigned)f2bf(a.w) << 16) | f2bf(a.z);
    o.z = ((unsigned)f2bf(b.y) << 16) | f2bf(b.x);
    o.w = ((unsigned)f2bf(b.w) << 16) | f2bf(b.z);
    __builtin_nontemporal_store(o, (uvec4*)&tb16[i]);
}

// ------------------------------------------------------------------
// Kernel 1 (R18): FUSED gather + MFMA MLP.
// Rationale: 3 rounds of separate-MLP fixes moved total <2%; kernel
// arithmetic says MLP dispatch should cost 10-25 us but the pipeline
// carries ~180 us of MLP+overhead. Fusing removes the 67 MB wsp
// round-trip and the opaque dispatch. Cost: level<->XCD L2 affinity
// is lost (R0-vs-R3 brackets gather penalty at <=1.4x).
// 2048 blocks x 256 thr; phase A: each thread gathers 16 levels for
// its point into LDS X (packed bf16, bit-identical to wsp path);
// phase B: 4 waves x 4 groups of 16 pts run the proven MFMA MLP.
// LDS 78.2 KB -> 2 blocks/CU; launch_bounds (256,2) caps VGPR 256.
// ------------------------------------------------------------------
#define GROUPS_F 4
#define SW1  32                  // Wd1 k-stride (shorts), rows 16B-aligned
#define SW   72                  // 64-k weight stride (shorts), rows 16B-aligned
#define SA   68                  // act k-stride (floats); 272B rows, 16B-aligned
#define OW1  0                   // 64*32 = 2048
#define OW2  2048                // 16*72 = 1152
#define OC1H 3200                // 64*72 = 4608
#define OC1L 7808
#define OC2H 12416
#define OC2L 17024
#define OC3H 21632               // 4*72 = 288 (rows 0-2 real, row 3 zero)
#define OC3L 21920
#define WTOT 22208               // shorts = 44,416 B

__global__ __launch_bounds__(256, 2)
void ngp_fused(const float* __restrict__ pos,
               const unsigned int* __restrict__ tb16,
               const float* __restrict__ dirp,
               const float* __restrict__ Wd1, const float* __restrict__ bd1,
               const float* __restrict__ Wd2, const float* __restrict__ bd2,
               const float* __restrict__ Wc1, const float* __restrict__ bc1,
               const float* __restrict__ Wc2, const float* __restrict__ bc2,
               const float* __restrict__ Wc3, const float* __restrict__ bc3,
               float* __restrict__ out, int n)
{
    __shared__ short wsm[WTOT];                    // 44,416 B
    __shared__ unsigned int xf[256 * 16];          // 16,384 B packed features
    __shared__ float act[4 * 16 * SA];             // 17,408 B
    const int tid = threadIdx.x;

    // ---- weight staging (identical to proven MLP kernel, MT=256) ----
    for (int t = tid; t < WTOT; t += 256) wsm[t] = 0;
    __syncthreads();
    for (int g = tid; g < 32 * 64; g += 256) {           // Wd1 (32,64) single
        const int k = g >> 6, nn = g & 63;
        wsm[OW1 + nn * SW1 + k] = f2bf(Wd1[g]);
    }
    for (int g = tid; g < 64 * 16; g += 256) {           // Wd2 (64,16) single
        const int k = g >> 4, nn = g & 15;
        wsm[OW2 + nn * SW + k] = f2bf(Wd2[g]);
    }
    for (int g = tid; g < 41 * 64; g += 256) {           // Wc1 (41,64) hi+lo
        const int k = g >> 6, nn = g & 63;
        const float w = Wc1[g];
        const unsigned short hh = f2bf(w);
        wsm[OC1H + nn * SW + k] = hh;
        wsm[OC1L + nn * SW + k] = f2bf(w - b2f(hh));
    }
    for (int g = tid; g < 64 * 64; g += 256) {           // Wc2 (64,64) hi+lo
        const int k = g >> 6, nn = g & 63;
        const float w = Wc2[g];
        const unsigned short hh = f2bf(w);
        wsm[OC2H + nn * SW + k] = hh;
        wsm[OC2L + nn * SW + k] = f2bf(w - b2f(hh));
    }
    for (int g = tid; g < 64 * 3; g += 256) {            // Wc3 (64,3) hi+lo
        const int k = g / 3, nn = g - 3 * k;
        const float w = Wc3[g];
        const unsigned short hh = f2bf(w);
        wsm[OC3H + nn * SW + k] = hh;
        wsm[OC3L + nn * SW + k] = f2bf(w - b2f(hh));
    }

    // ---- phase A: gather 16 levels for point ptg (bit-identical math) ----
    {
        const int ptg = blockIdx.x * 256 + tid;
        const float px = pos[3 * ptg + 0];
        const float py = pos[3 * ptg + 1];
        const float pz = pos[3 * ptg + 2];
#pragma unroll 2
        for (int l = 0; l < LEVELS; ++l) {
            const float resf = (float)(16 << l);
            const float tx = px * resf, ty = py * resf, tz = pz * resf;
            const float fx = floorf(tx), fy = floorf(ty), fz = floorf(tz);
            const float wx = tx - fx, wy = ty - fy, wz = tz - fz;
            const unsigned ix = (unsigned)(int)fx;
            const unsigned iy = (unsigned)(int)fy;
            const unsigned iz = (unsigned)(int)fz;
            const unsigned hy0 = iy * 2654435761u, hy1 = hy0 + 2654435761u;
            const unsigned hz0 = iz * 805459861u,  hz1 = hz0 + 805459861u;
            const unsigned ix1 = ix + 1u;

            const unsigned int* tb = tb16 + (size_t)l * TBL;
            const unsigned hA = hy0 ^ hz0;
            const unsigned hB = hy0 ^ hz1;
            const unsigned hC = hy1 ^ hz0;
            const unsigned hD = hy1 ^ hz1;

            unsigned eA0, eA1, eB0, eB1, eC0, eC1, eD0, eD1;
            if ((ix & 1u) == 0u) {
                const uint2 pA = *(const uint2*)&tb[((ix ^ hA) & TMASK) & ~1u];
                const uint2 pB = *(const uint2*)&tb[((ix ^ hB) & TMASK) & ~1u];
                const uint2 pC = *(const uint2*)&tb[((ix ^ hC) & TMASK) & ~1u];
                const uint2 pD = *(const uint2*)&tb[((ix ^ hD) & TMASK) & ~1u];
                const unsigned sA = hA & 1u, sB = hB & 1u, sC = hC & 1u, sD = hD & 1u;
                eA0 = sA ? pA.y : pA.x;  eA1 = sA ? pA.x : pA.y;
                eB0 = sB ? pB.y : pB.x;  eB1 = sB ? pB.x : pB.y;
                eC0 = sC ? pC.y : pC.x;  eC1 = sC ? pC.x : pC.y;
                eD0 = sD ? pD.y : pD.x;  eD1 = sD ? pD.x : pD.y;
            } else {
                eA0 = tb[(ix  ^ hA) & TMASK];  eA1 = tb[(ix1 ^ hA) & TMASK];
                eB0 = tb[(ix  ^ hB) & TMASK];  eB1 = tb[(ix1 ^ hB) & TMASK];
                eC0 = tb[(ix  ^ hC) & TMASK];  eC1 = tb[(ix1 ^ hC) & TMASK];
                eD0 = tb[(ix  ^ hD) & TMASK];  eD1 = tb[(ix1 ^ hD) & TMASK];
            }

#define UNPX(e) __uint_as_float((e) << 16)
#define UNPY(e) __uint_as_float((e) & 0xffff0000u)

            const float ux = 1.f - wx, uy = 1.f - wy, uz = 1.f - wz;
            const float c000 = ux * uy * uz, c001 = ux * uy * wz;
            const float c010 = ux * wy * uz, c011 = ux * wy * wz;
            const float c100 = wx * uy * uz, c101 = wx * uy * wz;
            const float c110 = wx * wy * uz, c111 = wx * wy * wz;

            float f0 = UNPX(eA0) * c000, f1 = UNPY(eA0) * c000;
            f0 = fmaf(UNPX(eB0), c001, f0); f1 = fmaf(UNPY(eB0), c001, f1);
            f0 = fmaf(UNPX(eC0), c010, f0); f1 = fmaf(UNPY(eC0), c010, f1);
            f0 = fmaf(UNPX(eD0), c011, f0); f1 = fmaf(UNPY(eD0), c011, f1);
            f0 = fmaf(UNPX(eA1), c100, f0); f1 = fmaf(UNPY(eA1), c100, f1);
            f0 = fmaf(UNPX(eB1), c101, f0); f1 = fmaf(UNPY(eB1), c101, f1);
            f0 = fmaf(UNPX(eC1), c110, f0); f1 = fmaf(UNPY(eC1), c110, f1);
            f0 = fmaf(UNPX(eD1), c111, f0); f1 = fmaf(UNPY(eD1), c111, f1);

            xf[tid * 16 + l] = ((unsigned)f2bf(f1) << 16) | f2bf(f0);
        }
    }
    __syncthreads();

    // ---- phase B: MFMA MLP, 4 waves x GROUPS_F groups of 16 pts ----
    const int wid = tid >> 6;              // 0..3
    const int lane = tid & 63;
    const int ln = lane & 15;
    const int qd = lane >> 4;
    float* A = act + wid * (16 * SA);

    float bd1v[4], bc1v[4], bc2v[4];
#pragma unroll
    for (int t = 0; t < 4; ++t) {
        bd1v[t] = bd1[t * 16 + ln];
        bc1v[t] = bc1[t * 16 + ln];
        bc2v[t] = bc2[t * 16 + ln];
    }
    const float bd2v = bd2[ln];
    const float bc3v = (ln < 3) ? bc3[ln] : 0.f;

#define LOAD_SPLIT(ah, al, k0)                                   \
    {                                                            \
        _Pragma("unroll")                                        \
        for (int j = 0; j < 8; ++j) {                            \
            const float v = A[ln * SA + (k0) + j];               \
            const unsigned short hb = f2bf(v);                   \
            ah[j] = (short)hb;                                   \
            al[j] = (short)f2bf(v - b2f(hb));                    \
        }                                                        \
    }

#define SPLIT_TILE(acc, ah0, ah1, al0, al1, OH, OL, row)                                          \
    {                                                                                             \
        const bf16x8 bh0 = *(const bf16x8*)&wsm[(OH) + (row) * SW + qd * 8];                      \
        const bf16x8 bh1 = *(const bf16x8*)&wsm[(OH) + (row) * SW + 32 + qd * 8];                 \
        acc = __builtin_amdgcn_mfma_f32_16x16x32_bf16(ah0, bh0, acc, 0, 0, 0);                    \
        acc = __builtin_amdgcn_mfma_f32_16x16x32_bf16(ah1, bh1, acc, 0, 0, 0);                    \
        acc = __builtin_amdgcn_mfma_f32_16x16x32_bf16(al0, bh0, acc, 0, 0, 0);                    \
        acc = __builtin_amdgcn_mfma_f32_16x16x32_bf16(al1, bh1, acc, 0, 0, 0);                    \
        const bf16x8 bl0 = *(const bf16x8*)&wsm[(OL) + (row) * SW + qd * 8];                      \
        const bf16x8 bl1 = *(const bf16x8*)&wsm[(OL) + (row) * SW + 32 + qd * 8];                 \
        acc = __builtin_amdgcn_mfma_f32_16x16x32_bf16(ah0, bl0, acc, 0, 0, 0);                    \
        acc = __builtin_amdgcn_mfma_f32_16x16x32_bf16(ah1, bl1, acc, 0, 0, 0);                    \
    }

    // dirp prefetch for group 0
    const int pt0 = blockIdx.x * 256 + wid * 64 + ln;
    float dq0 = dirp[3 * pt0 + 0];
    float dq1 = dirp[3 * pt0 + 1];
    float dq2 = dirp[3 * pt0 + 2];

#pragma unroll 1
    for (int grp = 0; grp < GROUPS_F; ++grp) {
        const int ptl_base = wid * 64 + grp * 16;               // block-local
        const int pt_base = blockIdx.x * 256 + ptl_base;        // global
        const int pt = pt_base + ln;

        // X from LDS: features (levels qd*4..qd*4+3) of point ln
        bf16x8 ax;
        {
            const uvec4 xr = *(const uvec4*)&xf[(ptl_base + ln) * 16 + qd * 4];
            ax[0] = (short)(xr.x & 0xffffu); ax[1] = (short)(xr.x >> 16);
            ax[2] = (short)(xr.y & 0xffffu); ax[3] = (short)(xr.y >> 16);
            ax[4] = (short)(xr.z & 0xffffu); ax[5] = (short)(xr.z >> 16);
            ax[6] = (short)(xr.w & 0xffffu); ax[7] = (short)(xr.w >> 16);
        }
        const float ddx = dq0, ddy = dq1, ddz = dq2;

        if (grp + 1 < GROUPS_F) {
            const int ptn = pt + 16;
            dq0 = dirp[3 * ptn + 0];
            dq1 = dirp[3 * ptn + 1];
            dq2 = dirp[3 * ptn + 2];
        }

        // ---- d1: Y[16x64] = X @ Wd1 (single bf16) ----
#pragma unroll
        for (int t = 0; t < 4; ++t) {
            const bf16x8 b = *(const bf16x8*)&wsm[OW1 + (t * 16 + ln) * SW1 + qd * 8];
            const float bv = bd1v[t];
            f32x4 acc = {bv, bv, bv, bv};
            acc = __builtin_amdgcn_mfma_f32_16x16x32_bf16(ax, b, acc, 0, 0, 0);
#pragma unroll
            for (int r = 0; r < 4; ++r)
                A[(qd * 4 + r) * SA + t * 16 + ln] = fmaxf(acc[r], 0.f);   // fp32
        }

        // ---- d2: D[16x16] = relu(Y) @ Wd2 (single bf16) ----
        {
            bf16x8 a0, a1;
#pragma unroll
            for (int j = 0; j < 8; ++j) a0[j] = (short)f2bf(A[ln * SA + qd * 8 + j]);
#pragma unroll
            for (int j = 0; j < 8; ++j) a1[j] = (short)f2bf(A[ln * SA + 32 + qd * 8 + j]);
            const bf16x8 b0 = *(const bf16x8*)&wsm[OW2 + ln * SW + qd * 8];
            const bf16x8 b1 = *(const bf16x8*)&wsm[OW2 + ln * SW + 32 + qd * 8];
            const float bv = bd2v;
            f32x4 acc = {bv, bv, bv, bv};
            acc = __builtin_amdgcn_mfma_f32_16x16x32_bf16(a0, b0, acc, 0, 0, 0);
            acc = __builtin_amdgcn_mfma_f32_16x16x32_bf16(a1, b1, acc, 0, 0, 0);
            if (ln == 15) {
#pragma unroll
                for (int r = 0; r < 4; ++r)
                    out[3 * n + pt_base + qd * 4 + r] = fmaxf(acc[r], 0.f);    // sigma
            }
#pragma unroll
            for (int r = 0; r < 4; ++r)
                A[(qd * 4 + r) * SA + ln] = acc[r];        // raw D fp32, k=0..15
        }

        // ---- SH -> act fp32, k=16..40 (k=41..63 stale, Wc1 rows zeroed) ----
        {
            const float dxv = ddx, dyv = ddy, dzv = ddz;
            const float x2 = dxv * dxv, y2 = dyv * dyv, z2 = dzv * dzv;
            const float xy = dxv * dyv, xz = dxv * dzv, yz = dyv * dzv;
            const float x4 = x2 * x2, y4 = y2 * y2;
            const float c0  = (float)(0.5 * sqrt(1.0 / M_PI));
            const float c1  = (float)(0.5 * sqrt(3.0 / M_PI));
            const float sub = (float)(0.25 * sqrt(5.0 / M_PI));
            const float v1  = (float)(0.25 * sqrt(15.0 / M_PI));
            const float v2  = (float)(0.5 * sqrt(15.0 / M_PI));
            const float v3  = (float)(0.75 * sqrt(5.0 / M_PI));
            const float w1c = (float)(0.25 * sqrt(105.0 / M_PI));
            const float w2c = (float)(0.5 * sqrt(105.0 / M_PI));
            const float w3c = (float)(0.25 * sqrt(35.0 / (2.0 * M_PI)));
            const float w4c = (float)(0.5 * sqrt(7.0 / (6.0 * M_PI)));
            float* Ash = &A[ln * SA + 16];
#define SH_PUT(i, expr) { if (((i) & 3) == qd) Ash[i] = (expr); }
            SH_PUT(0,  c0)
            SH_PUT(1,  -c1 * dyv)
            SH_PUT(2,   c1 * dzv)
            SH_PUT(3,  -c1 * dxv)
            SH_PUT(4,   v2 * xy)
            SH_PUT(5,  -v2 * yz)
            SH_PUT(6,   v3 * z2 - sub)
            SH_PUT(7,  -v2 * xz)
            SH_PUT(8,   v1 * x2 - v1 * y2)
            SH_PUT(9,  -w3c * dyv * (3.0f * x2 - y2))
            SH_PUT(10,  w2c * xy * dzv)
            SH_PUT(11,  w4c * dyv * (1.5f - 7.5f * z2))
            SH_PUT(12,  1.24392110863372f * dzv * (1.5f * z2 - 0.5f) - 0.497568443453487f * dzv)
            SH_PUT(13,  w4c * dxv * (1.5f - 7.5f * z2))
            SH_PUT(14,  w1c * dzv * (x2 - y2))
            SH_PUT(15, -w3c * dxv * (x2 - 3.0f * y2))
            SH_PUT(16,  2.5033429417967f * xy * (x2 - y2))
            SH_PUT(17, -1.77013076977993f * yz * (3.0f * x2 - y2))
            SH_PUT(18,  0.126156626101008f * xy * (52.5f * z2 - 7.5f))
            SH_PUT(19,  0.267618617422916f * dyv * (2.33333333333333f * dzv * (1.5f - 7.5f * z2) + 4.0f * dzv))
            SH_PUT(20,  1.48099765681286f * dzv * (1.66666666666667f * dzv * (1.5f * z2 - 0.5f) - 0.666666666666667f * dzv)
                        - 0.952069922236839f * z2 + 0.317356640745613f)
            SH_PUT(21,  0.267618617422916f * dxv * (2.33333333333333f * dzv * (1.5f - 7.5f * z2) + 4.0f * dzv))
            SH_PUT(22,  0.063078313050504f * (x2 - y2) * (52.5f * z2 - 7.5f))
            SH_PUT(23, -1.77013076977993f * xz * (x2 - 3.0f * y2))
            SH_PUT(24, -3.75501441269506f * x2 * y2 + 0.625835735449176f * x4 + 0.625835735449176f * y4)
#undef SH_PUT
        }

        // ---- c1: H1 = [D|SH|0] @ Wc1 (split) ----
        {
            bf16x8 ah0, ah1, al0, al1;
            LOAD_SPLIT(ah0, al0, qd * 8)
            LOAD_SPLIT(ah1, al1, 32 + qd * 8)
#pragma unroll
            for (int t = 0; t < 4; ++t) {
                const float bv = bc1v[t];
                f32x4 acc = {bv, bv, bv, bv};
                SPLIT_TILE(acc, ah0, ah1, al0, al1, OC1H, OC1L, t * 16 + ln)
#pragma unroll
                for (int r = 0; r < 4; ++r)
                    A[(qd * 4 + r) * SA + t * 16 + ln] = fmaxf(acc[r], 0.f);
                __builtin_amdgcn_sched_barrier(0);
            }
        }

        // ---- c2: H2 = relu(H1) @ Wc2 (split) ----
        {
            bf16x8 ah0, ah1, al0, al1;
            LOAD_SPLIT(ah0, al0, qd * 8)
            LOAD_SPLIT(ah1, al1, 32 + qd * 8)
#pragma unroll
            for (int t = 0; t < 4; ++t) {
                const float bv = bc2v[t];
                f32x4 acc = {bv, bv, bv, bv};
                SPLIT_TILE(acc, ah0, ah1, al0, al1, OC2H, OC2L, t * 16 + ln)
#pragma unroll
                for (int r = 0; r < 4; ++r)
                    A[(qd * 4 + r) * SA + t * 16 + ln] = fmaxf(acc[r], 0.f);
                __builtin_amdgcn_sched_barrier(0);
            }
        }

        // ---- c3 + sigmoid: R = relu(H2) @ Wc3 (split) ----
        {
            bf16x8 ah0, ah1, al0, al1;
            LOAD_SPLIT(ah0, al0, qd * 8)
            LOAD_SPLIT(ah1, al1, 32 + qd * 8)
            const float bv = bc3v;
            f32x4 acc = {bv, bv, bv, bv};
            SPLIT_TILE(acc, ah0, ah1, al0, al1, OC3H, OC3L, (ln & 3))
            if (ln < 3) {
#pragma unroll
                for (int r = 0; r < 4; ++r)
                    out[3 * (pt_base + qd * 4 + r) + ln] = 1.f / (1.f + expf(-acc[r]));
            }
        }
    }
}

// ------------------------------------------------------------------
// Fallback: round-1 fused kernel (if ws too small / n not 2^19) — proven
// ------------------------------------------------------------------
__global__ __launch_bounds__(256)
void nerf_fused(const float* __restrict__ pos,
                const float* __restrict__ dirp,
                const float* __restrict__ tables,
                const float* __restrict__ Wd1, const float* __restrict__ bd1,
                const float* __restrict__ Wd2, const float* __restrict__ bd2,
                const float* __restrict__ Wc1, const float* __restrict__ bc1,
                const float* __restrict__ Wc2, const float* __restrict__ bc2,
                const float* __restrict__ Wc3, const float* __restrict__ bc3,
                float* __restrict__ out, int n)
{
    const int idx = blockIdx.x * blockDim.x + threadIdx.x;
    if (idx >= n) return;
    const float px = pos[3 * idx + 0], py = pos[3 * idx + 1], pz = pos[3 * idx + 2];
    float y[64];
#pragma unroll
    for (int j = 0; j < 64; ++j) y[j] = bd1[j];
#pragma unroll
    for (int l = 0; l < LEVELS; ++l) {
        const float resf = (float)(16 << l);
        const float tx = px * resf, ty = py * resf, tz = pz * resf;
        const float fx = floorf(tx), fy = floorf(ty), fz = floorf(tz);
        const float wx = tx - fx, wy = ty - fy, wz = tz - fz;
        const unsigned ix = (unsigned)(int)fx, iy = (unsigned)(int)fy, iz = (unsigned)(int)fz;
        const unsigned hy0 = iy * 2654435761u, hy1 = hy0 + 2654435761u;
        const unsigned hz0 = iz * 805459861u,  hz1 = hz0 + 805459861u;
        const unsigned ix1 = ix + 1u;
        const float2* tb = (const float2*)tables + (size_t)l * TBL;
        const float2 e000 = tb[(ix  ^ hy0 ^ hz0) & TMASK];
        const float2 e001 = tb[(ix  ^ hy0 ^ hz1) & TMASK];
        const float2 e010 = tb[(ix  ^ hy1 ^ hz0) & TMASK];
        const float2 e011 = tb[(ix  ^ hy1 ^ hz1) & TMASK];
        const float2 e100 = tb[(ix1 ^ hy0 ^ hz0) & TMASK];
        const float2 e101 = tb[(ix1 ^ hy0 ^ hz1) & TMASK];
        const float2 e110 = tb[(ix1 ^ hy1 ^ hz0) & TMASK];
        const float2 e111 = tb[(ix1 ^ hy1 ^ hz1) & TMASK];
        const float ux = 1.f - wx, uy = 1.f - wy, uz = 1.f - wz;
        const float c000 = ux*uy*uz, c001 = ux*uy*wz, c010 = ux*wy*uz, c011 = ux*wy*wz;
        const float c100 = wx*uy*uz, c101 = wx*uy*wz, c110 = wx*wy*uz, c111 = wx*wy*wz;
        float f0 = e000.x*c000, f1 = e000.y*c000;
        f0 = fmaf(e001.x,c001,f0); f1 = fmaf(e001.y,c001,f1);
        f0 = fmaf(e010.x,c010,f0); f1 = fmaf(e010.y,c010,f1);
        f0 = fmaf(e011.x,c011,f0); f1 = fmaf(e011.y,c011,f1);
        f0 = fmaf(e100.x,c100,f0); f1 = fmaf(e100.y,c100,f1);
        f0 = fmaf(e101.x,c101,f0); f1 = fmaf(e101.y,c101,f1);
        f0 = fmaf(e110.x,c110,f0); f1 = fmaf(e110.y,c110,f1);
        f0 = fmaf(e111.x,c111,f0); f1 = fmaf(e111.y,c111,f1);
        const float* w0 = Wd1 + (size_t)(2 * l) * 64;
#pragma unroll
        for (int j = 0; j < 64; ++j)
            y[j] = fmaf(f0, w0[j], fmaf(f1, w0[64 + j], y[j]));
    }
    float d[16];
#pragma unroll
    for (int k = 0; k < 16; ++k) d[k] = bd2[k];
#pragma unroll
    for (int j = 0; j < 64; ++j) {
        const float a = fmaxf(y[j], 0.f);
#pragma unroll
        for (int k = 0; k < 16; ++k) d[k] = fmaf(a, Wd2[j * 16 + k], d[k]);
    }
    out[3 * n + idx] = fmaxf(d[15], 0.f);
    const float dx = dirp[3*idx], dy = dirp[3*idx+1], dz = dirp[3*idx+2];
    float sh[25];
    SH_BLOCK(sh, dx, dy, dz)
    float h1[64];
#pragma unroll
    for (int j = 0; j < 64; ++j) h1[j] = bc1[j];
#pragma unroll
    for (int i = 0; i < 16; ++i) {
#pragma unroll
        for (int j = 0; j < 64; ++j) h1[j] = fmaf(d[i], Wc1[i * 64 + j], h1[j]);
    }
#pragma unroll
    for (int s = 0; s < 25; ++s) {
#pragma unroll
        for (int j = 0; j < 64; ++j) h1[j] = fmaf(sh[s], Wc1[(16 + s) * 64 + j], h1[j]);
    }
    float h2[64];
#pragma unroll
    for (int j = 0; j < 64; ++j) h2[j] = bc2[j];
#pragma unroll
    for (int i = 0; i < 64; ++i) {
        const float a = fmaxf(h1[i], 0.f);
#pragma unroll
        for (int j = 0; j < 64; ++j) h2[j] = fmaf(a, Wc2[i * 64 + j], h2[j]);
    }
    float r0 = bc3[0], r1 = bc3[1], r2 = bc3[2];
#pragma unroll
    for (int j = 0; j < 64; ++j) {
        const float a = fmaxf(h2[j], 0.f);
        r0 = fmaf(a, Wc3[j * 3 + 0], r0);
        r1 = fmaf(a, Wc3[j * 3 + 1], r1);
        r2 = fmaf(a, Wc3[j * 3 + 2], r2);
    }
    out[3 * idx + 0] = 1.f / (1.f + expf(-r0));
    out[3 * idx + 1] = 1.f / (1.f + expf(-r1));
    out[3 * idx + 2] = 1.f / (1.f + expf(-r2));
}

extern "C" void kernel_launch(void* const* d_in, const int* in_sizes, int n_in,
                              void* d_out, int out_size, void* d_ws, size_t ws_size,
                              hipStream_t stream) {
    const float* pos    = (const float*)d_in[0];
    const float* dir    = (const float*)d_in[1];
    const float* tables = (const float*)d_in[2];
    const float* Wd1 = (const float*)d_in[3];
    const float* bd1 = (const float*)d_in[4];
    const float* Wd2 = (const float*)d_in[5];
    const float* bd2 = (const float*)d_in[6];
    const float* Wc1 = (const float*)d_in[7];
    const float* bc1 = (const float*)d_in[8];
    const float* Wc2 = (const float*)d_in[9];
    const float* bc2 = (const float*)d_in[10];
    const float* Wc3 = (const float*)d_in[11];
    const float* bc3 = (const float*)d_in[12];

    const int n = in_sizes[0] / 3;
    const int blocks = (n + 255) / 256;

    // workspace layout: [0, LEVELS*TBL*4) packed-bf16 tables
    if (ws_size >= (size_t)LEVELS * TBL * 4 && n == 524288) {
        unsigned int* tb16 = (unsigned int*)d_ws;
        const int total = LEVELS * TBL;
        cvt_tables<<<total / 1024, 256, 0, stream>>>(tables, tb16, total);
        ngp_fused<<<n / 256, 256, 0, stream>>>(pos, tb16, dir,
                                               Wd1, bd1, Wd2, bd2,
                                               Wc1, bc1, Wc2, bc2, Wc3, bc3,
                                               (float*)d_out, n);
    } else {
        nerf_fused<<<blocks, 256, 0, stream>>>(pos, dir, tables,
                                               Wd1, bd1, Wd2, bd2,
                                               Wc1, bc1, Wc2, bc2, Wc3, bc3,
                                               (float*)d_out, n);
    }
}

// Round 9
// 355.231 us; speedup vs baseline: 1.2108x; 1.2108x over previous
//
#include <hip/hip_runtime.h>
#include <math.h>

#define LEVELS 16
#define TBL 524288          // 2^19 entries per level
#define TMASK (TBL - 1)

typedef short bf16x8 __attribute__((ext_vector_type(8)));
typedef float f32x4  __attribute__((ext_vector_type(4)));
typedef float fvec4  __attribute__((ext_vector_type(4)));
typedef unsigned int uvec4 __attribute__((ext_vector_type(4)));

static __device__ __forceinline__ unsigned short f2bf(float x) {
    unsigned u = __float_as_uint(x);
    u += 0x7fffu + ((u >> 16) & 1u);    // RNE
    return (unsigned short)(u >> 16);
}
static __device__ __forceinline__ float b2f(unsigned short h) {
    return __uint_as_float(((unsigned)h) << 16);
}

// SH degree-4 block, constants computed exactly as round-1 (verified correct).
#define SH_BLOCK(sh, dx, dy, dz)                                                          \
    const float x2 = dx * dx, y2 = dy * dy, z2 = dz * dz;                                 \
    const float xy = dx * dy, xz = dx * dz, yz = dy * dz;                                 \
    const float x4 = x2 * x2, y4 = y2 * y2;                                               \
    const float c0  = (float)(0.5 * sqrt(1.0 / M_PI));                                    \
    const float c1  = (float)(0.5 * sqrt(3.0 / M_PI));                                    \
    const float sub = (float)(0.25 * sqrt(5.0 / M_PI));                                   \
    const float v1  = (float)(0.25 * sqrt(15.0 / M_PI));                                  \
    const float v2  = (float)(0.5 * sqrt(15.0 / M_PI));                                   \
    const float v3  = (float)(0.75 * sqrt(5.0 / M_PI));                                   \
    const float w1c = (float)(0.25 * sqrt(105.0 / M_PI));                                 \
    const float w2c = (float)(0.5 * sqrt(105.0 / M_PI));                                  \
    const float w3c = (float)(0.25 * sqrt(35.0 / (2.0 * M_PI)));                          \
    const float w4c = (float)(0.5 * sqrt(7.0 / (6.0 * M_PI)));                            \
    sh[0] = c0;                                                                           \
    sh[1] = -c1 * dy;                                                                     \
    sh[2] =  c1 * dz;                                                                     \
    sh[3] = -c1 * dx;                                                                     \
    sh[4] =  v2 * xy;                                                                     \
    sh[5] = -v2 * yz;                                                                     \
    sh[6] =  v3 * z2 - sub;                                                               \
    sh[7] = -v2 * xz;                                                                     \
    sh[8] =  v1 * x2 - v1 * y2;                                                           \
    sh[9]  = -w3c * dy * (3.0f * x2 - y2);                                                \
    sh[10] =  w2c * xy * dz;                                                              \
    sh[11] =  w4c * dy * (1.5f - 7.5f * z2);                                              \
    sh[12] =  1.24392110863372f * dz * (1.5f * z2 - 0.5f) - 0.497568443453487f * dz;      \
    sh[13] =  w4c * dx * (1.5f - 7.5f * z2);                                              \
    sh[14] =  w1c * dz * (x2 - y2);                                                       \
    sh[15] = -w3c * dx * (x2 - 3.0f * y2);                                                \
    sh[16] =  2.5033429417967f * xy * (x2 - y2);                                          \
    sh[17] = -1.77013076977993f * yz * (3.0f * x2 - y2);                                  \
    sh[18] =  0.126156626101008f * xy * (52.5f * z2 - 7.5f);                              \
    sh[19] =  0.267618617422916f * dy * (2.33333333333333f * dz * (1.5f - 7.5f * z2) + 4.0f * dz); \
    sh[20] =  1.48099765681286f * dz * (1.66666666666667f * dz * (1.5f * z2 - 0.5f) - 0.666666666666667f * dz) \
              - 0.952069922236839f * z2 + 0.317356640745613f;                             \
    sh[21] =  0.267618617422916f * dx * (2.33333333333333f * dz * (1.5f - 7.5f * z2) + 4.0f * dz); \
    sh[22] =  0.063078313050504f * (x2 - y2) * (52.5f * z2 - 7.5f);                       \
    sh[23] = -1.77013076977993f * xz * (x2 - 3.0f * y2);                                  \
    sh[24] = -3.75501441269506f * x2 * y2 + 0.625835735449176f * x4 + 0.625835735449176f * y4;

// Per-point SH emit into an act row pointer, predicated by qd (bit-identical exprs).
#define SH_EMIT(Ash, DXV, DYV, DZV)                                                        \
    {                                                                                      \
        const float sx2 = (DXV)*(DXV), sy2 = (DYV)*(DYV), sz2 = (DZV)*(DZV);               \
        const float sxy = (DXV)*(DYV), sxz = (DXV)*(DZV), syz = (DYV)*(DZV);               \
        const float sx4 = sx2*sx2, sy4 = sy2*sy2;                                          \
        const float k0  = (float)(0.5 * sqrt(1.0 / M_PI));                                 \
        const float k1  = (float)(0.5 * sqrt(3.0 / M_PI));                                 \
        const float ksub= (float)(0.25 * sqrt(5.0 / M_PI));                                \
        const float kv1 = (float)(0.25 * sqrt(15.0 / M_PI));                               \
        const float kv2 = (float)(0.5 * sqrt(15.0 / M_PI));                                \
        const float kv3 = (float)(0.75 * sqrt(5.0 / M_PI));                                \
        const float kw1 = (float)(0.25 * sqrt(105.0 / M_PI));                              \
        const float kw2 = (float)(0.5 * sqrt(105.0 / M_PI));                               \
        const float kw3 = (float)(0.25 * sqrt(35.0 / (2.0 * M_PI)));                       \
        const float kw4 = (float)(0.5 * sqrt(7.0 / (6.0 * M_PI)));                         \
        if ((0  & 3) == qd) (Ash)[0]  = k0;                                                \
        if ((1  & 3) == qd) (Ash)[1]  = -k1 * (DYV);                                       \
        if ((2  & 3) == qd) (Ash)[2]  =  k1 * (DZV);                                       \
        if ((3  & 3) == qd) (Ash)[3]  = -k1 * (DXV);                                       \
        if ((4  & 3) == qd) (Ash)[4]  =  kv2 * sxy;                                        \
        if ((5  & 3) == qd) (Ash)[5]  = -kv2 * syz;                                        \
        if ((6  & 3) == qd) (Ash)[6]  =  kv3 * sz2 - ksub;                                 \
        if ((7  & 3) == qd) (Ash)[7]  = -kv2 * sxz;                                        \
        if ((8  & 3) == qd) (Ash)[8]  =  kv1 * sx2 - kv1 * sy2;                            \
        if ((9  & 3) == qd) (Ash)[9]  = -kw3 * (DYV) * (3.0f * sx2 - sy2);                 \
        if ((10 & 3) == qd) (Ash)[10] =  kw2 * sxy * (DZV);                                \
        if ((11 & 3) == qd) (Ash)[11] =  kw4 * (DYV) * (1.5f - 7.5f * sz2);                \
        if ((12 & 3) == qd) (Ash)[12] =  1.24392110863372f * (DZV) * (1.5f * sz2 - 0.5f) - 0.497568443453487f * (DZV); \
        if ((13 & 3) == qd) (Ash)[13] =  kw4 * (DXV) * (1.5f - 7.5f * sz2);                \
        if ((14 & 3) == qd) (Ash)[14] =  kw1 * (DZV) * (sx2 - sy2);                        \
        if ((15 & 3) == qd) (Ash)[15] = -kw3 * (DXV) * (sx2 - 3.0f * sy2);                 \
        if ((16 & 3) == qd) (Ash)[16] =  2.5033429417967f * sxy * (sx2 - sy2);             \
        if ((17 & 3) == qd) (Ash)[17] = -1.77013076977993f * syz * (3.0f * sx2 - sy2);     \
        if ((18 & 3) == qd) (Ash)[18] =  0.126156626101008f * sxy * (52.5f * sz2 - 7.5f);  \
        if ((19 & 3) == qd) (Ash)[19] =  0.267618617422916f * (DYV) * (2.33333333333333f * (DZV) * (1.5f - 7.5f * sz2) + 4.0f * (DZV)); \
        if ((20 & 3) == qd) (Ash)[20] =  1.48099765681286f * (DZV) * (1.66666666666667f * (DZV) * (1.5f * sz2 - 0.5f) - 0.666666666666667f * (DZV)) \
                                         - 0.952069922236839f * sz2 + 0.317356640745613f;  \
        if ((21 & 3) == qd) (Ash)[21] =  0.267618617422916f * (DXV) * (2.33333333333333f * (DZV) * (1.5f - 7.5f * sz2) + 4.0f * (DZV)); \
        if ((22 & 3) == qd) (Ash)[22] =  0.063078313050504f * (sx2 - sy2) * (52.5f * sz2 - 7.5f); \
        if ((23 & 3) == qd) (Ash)[23] = -1.77013076977993f * sxz * (sx2 - 3.0f * sy2);     \
        if ((24 & 3) == qd) (Ash)[24] = -3.75501441269506f * sx2 * sy2 + 0.625835735449176f * sx4 + 0.625835735449176f * sy4; \
    }

// ------------------------------------------------------------------
// Kernel 0: pack fp32 tables -> bf16x2 (one uint per entry).
// ------------------------------------------------------------------
__global__ __launch_bounds__(256)
void cvt_tables(const float* __restrict__ tables,
                unsigned int* __restrict__ tb16, int total)
{
    const int i = (blockIdx.x * 256 + threadIdx.x) * 4;   // 4 entries/thread
    if (i >= total) return;
    const fvec4 a = __builtin_nontemporal_load((const fvec4*)(tables + 2 * (size_t)i));
    const fvec4 b = __builtin_nontemporal_load((const fvec4*)(tables + 2 * (size_t)i) + 1);
    uvec4 o;
    o.x = ((unsigned)f2bf(a.y) << 16) | f2bf(a.x);
    o.y = ((unsigned)f2bf(a.w) << 16) | f2bf(a.z);
    o.z = ((unsigned)f2bf(b.y) << 16) | f2bf(b.x);
    o.w = ((unsigned)f2bf(b.w) << 16) | f2bf(b.z);
    __builtin_nontemporal_store(o, (uvec4*)&tb16[i]);
}

// ------------------------------------------------------------------
// Kernel 1 (R19): hash-grid gather, HALF the levels per dispatch.
// l = lbase + (b&7): one 2 MB table per XCD L2 (was two). Launched
// twice (lbase 0, 8). Each dispatch ~78 us -> the MLP dispatch
// finally becomes visible in the profiler top-5. Same math as R7.
// ------------------------------------------------------------------
__global__ __launch_bounds__(256)
void ngp_encode_lvl(const float* __restrict__ pos,
                    const unsigned int* __restrict__ tb16,
                    unsigned int* __restrict__ wsp, int n, int lbase)
{
    const int b = blockIdx.x;
    const int l = lbase + (b & 7);
    const int c = b >> 3;
    const int idx = c * 256 + threadIdx.x;
    if (idx >= n || l >= LEVELS) return;

    const float px = pos[3 * idx + 0];
    const float py = pos[3 * idx + 1];
    const float pz = pos[3 * idx + 2];

    const float resf = (float)(16 << l);
    const float tx = px * resf, ty = py * resf, tz = pz * resf;
    const float fx = floorf(tx), fy = floorf(ty), fz = floorf(tz);
    const float wx = tx - fx, wy = ty - fy, wz = tz - fz;
    const unsigned ix = (unsigned)(int)fx;
    const unsigned iy = (unsigned)(int)fy;
    const unsigned iz = (unsigned)(int)fz;
    const unsigned hy0 = iy * 2654435761u, hy1 = hy0 + 2654435761u;
    const unsigned hz0 = iz * 805459861u,  hz1 = hz0 + 805459861u;
    const unsigned ix1 = ix + 1u;

    const unsigned int* tb = tb16 + (size_t)l * TBL;
    const unsigned hA = hy0 ^ hz0;        // (y=0,z=0)
    const unsigned hB = hy0 ^ hz1;        // (y=0,z=1)
    const unsigned hC = hy1 ^ hz0;        // (y=1,z=0)
    const unsigned hD = hy1 ^ hz1;        // (y=1,z=1)

    unsigned eA0, eA1, eB0, eB1, eC0, eC1, eD0, eD1;   // e{combo}{x}
    if ((ix & 1u) == 0u) {
        // even ix: {ix^h, (ix+1)^h} = {m, m^1} -> one aligned 8B load
        const uint2 pA = *(const uint2*)&tb[((ix ^ hA) & TMASK) & ~1u];
        const uint2 pB = *(const uint2*)&tb[((ix ^ hB) & TMASK) & ~1u];
        const uint2 pC = *(const uint2*)&tb[((ix ^ hC) & TMASK) & ~1u];
        const uint2 pD = *(const uint2*)&tb[((ix ^ hD) & TMASK) & ~1u];
        const unsigned sA = hA & 1u, sB = hB & 1u, sC = hC & 1u, sD = hD & 1u;
        eA0 = sA ? pA.y : pA.x;  eA1 = sA ? pA.x : pA.y;
        eB0 = sB ? pB.y : pB.x;  eB1 = sB ? pB.x : pB.y;
        eC0 = sC ? pC.y : pC.x;  eC1 = sC ? pC.x : pC.y;
        eD0 = sD ? pD.y : pD.x;  eD1 = sD ? pD.x : pD.y;
    } else {
        eA0 = tb[(ix  ^ hA) & TMASK];  eA1 = tb[(ix1 ^ hA) & TMASK];
        eB0 = tb[(ix  ^ hB) & TMASK];  eB1 = tb[(ix1 ^ hB) & TMASK];
        eC0 = tb[(ix  ^ hC) & TMASK];  eC1 = tb[(ix1 ^ hC) & TMASK];
        eD0 = tb[(ix  ^ hD) & TMASK];  eD1 = tb[(ix1 ^ hD) & TMASK];
    }

#define UNPX(e) __uint_as_float((e) << 16)
#define UNPY(e) __uint_as_float((e) & 0xffff0000u)

    const float ux = 1.f - wx, uy = 1.f - wy, uz = 1.f - wz;
    const float c000 = ux * uy * uz, c001 = ux * uy * wz;
    const float c010 = ux * wy * uz, c011 = ux * wy * wz;
    const float c100 = wx * uy * uz, c101 = wx * uy * wz;
    const float c110 = wx * wy * uz, c111 = wx * wy * wz;

    float f0 = UNPX(eA0) * c000, f1 = UNPY(eA0) * c000;
    f0 = fmaf(UNPX(eB0), c001, f0); f1 = fmaf(UNPY(eB0), c001, f1);
    f0 = fmaf(UNPX(eC0), c010, f0); f1 = fmaf(UNPY(eC0), c010, f1);
    f0 = fmaf(UNPX(eD0), c011, f0); f1 = fmaf(UNPY(eD0), c011, f1);
    f0 = fmaf(UNPX(eA1), c100, f0); f1 = fmaf(UNPY(eA1), c100, f1);
    f0 = fmaf(UNPX(eB1), c101, f0); f1 = fmaf(UNPY(eB1), c101, f1);
    f0 = fmaf(UNPX(eC1), c110, f0); f1 = fmaf(UNPY(eC1), c110, f1);
    f0 = fmaf(UNPX(eD1), c111, f0); f1 = fmaf(UNPY(eD1), c111, f1);

    const unsigned int h0 = f2bf(f0);
    const unsigned int h1 = f2bf(f1);
    __builtin_nontemporal_store((h1 << 16) | h0, &wsp[(size_t)l * n + idx]);
}

// ------------------------------------------------------------------
// Kernel 2 (R19): split-precision MFMA MLP, 32 points per wave-iter.
// B-tiles (weights in LDS) are the dominant LDS traffic (60 b128 per
// 16 points). Loading each B-tile once for TWO 16-pt MFMA sets cuts
// weight-read traffic per point in half. Per-point MFMA order is
// unchanged -> bit-identical. 256-thr blocks (4 waves x 32 pts x
// GROUPS=8 = 1024 pts), 512 blocks; LDS 79,232 B -> 2 blocks/CU;
// launch_bounds (256,2) caps VGPR 256 (no spill possible).
// ------------------------------------------------------------------
#define GROUPS 8
#define SW1  32                  // Wd1 k-stride (shorts), rows 16B-aligned
#define SW   72                  // 64-k weight stride (shorts), rows 16B-aligned
#define SA   68                  // act k-stride (floats); 272B rows, 16B-aligned
#define OW1  0                   // 64*32 = 2048
#define OW2  2048                // 16*72 = 1152
#define OC1H 3200                // 64*72 = 4608
#define OC1L 7808
#define OC2H 12416
#define OC2L 17024
#define OC3H 21632               // 4*72 = 288 (rows 0-2 real, row 3 zero)
#define OC3L 21920
#define WTOT 22208               // shorts = 44,416 B; + act 34,816 B = 79,232 B

__global__ __launch_bounds__(256, 2)
void ngp_mlp_mfma4(const unsigned int* __restrict__ wsp,
                   const float* __restrict__ dirp,
                   const float* __restrict__ Wd1, const float* __restrict__ bd1,
                   const float* __restrict__ Wd2, const float* __restrict__ bd2,
                   const float* __restrict__ Wc1, const float* __restrict__ bc1,
                   const float* __restrict__ Wc2, const float* __restrict__ bc2,
                   const float* __restrict__ Wc3, const float* __restrict__ bc3,
                   float* __restrict__ out, int n)
{
    __shared__ short wsm[WTOT];
    __shared__ float act[4 * 32 * SA];     // 34,816 B
    const int tid = threadIdx.x;

    for (int t = tid; t < WTOT; t += 256) wsm[t] = 0;
    __syncthreads();

    for (int g = tid; g < 32 * 64; g += 256) {            // Wd1 (32,64) single
        const int k = g >> 6, nn = g & 63;
        wsm[OW1 + nn * SW1 + k] = f2bf(Wd1[g]);
    }
    for (int g = tid; g < 64 * 16; g += 256) {            // Wd2 (64,16) single
        const int k = g >> 4, nn = g & 15;
        wsm[OW2 + nn * SW + k] = f2bf(Wd2[g]);
    }
    for (int g = tid; g < 41 * 64; g += 256) {            // Wc1 (41,64) hi+lo
        const int k = g >> 6, nn = g & 63;
        const float w = Wc1[g];
        const unsigned short hh = f2bf(w);
        wsm[OC1H + nn * SW + k] = hh;
        wsm[OC1L + nn * SW + k] = f2bf(w - b2f(hh));
    }
    for (int g = tid; g < 64 * 64; g += 256) {            // Wc2 (64,64) hi+lo
        const int k = g >> 6, nn = g & 63;
        const float w = Wc2[g];
        const unsigned short hh = f2bf(w);
        wsm[OC2H + nn * SW + k] = hh;
        wsm[OC2L + nn * SW + k] = f2bf(w - b2f(hh));
    }
    for (int g = tid; g < 64 * 3; g += 256) {             // Wc3 (64,3) hi+lo
        const int k = g / 3, nn = g - 3 * k;
        const float w = Wc3[g];
        const unsigned short hh = f2bf(w);
        wsm[OC3H + nn * SW + k] = hh;
        wsm[OC3L + nn * SW + k] = f2bf(w - b2f(hh));
    }
    __syncthreads();

    const int wid = tid >> 6;              // 0..3
    const int lane = tid & 63;
    const int ln = lane & 15;
    const int qd = lane >> 4;
    float* A0 = act + wid * (32 * SA);     // rows 0-15: sub0
    float* A1 = A0 + 16 * SA;              // rows 16-31: sub1

    float bd1v[4], bc1v[4], bc2v[4];
#pragma unroll
    for (int t = 0; t < 4; ++t) {
        bd1v[t] = bd1[t * 16 + ln];
        bc1v[t] = bc1[t * 16 + ln];
        bc2v[t] = bc2[t * 16 + ln];
    }
    const float bd2v = bd2[ln];
    const float bc3v = (ln < 3) ? bc3[ln] : 0.f;

#define LOAD_SPLITP(AP, ah, al, k0)                              \
    {                                                            \
        _Pragma("unroll")                                        \
        for (int j = 0; j < 8; ++j) {                            \
            const float v = (AP)[ln * SA + (k0) + j];            \
            const unsigned short hb = f2bf(v);                   \
            ah[j] = (short)hb;                                   \
            al[j] = (short)f2bf(v - b2f(hb));                    \
        }                                                        \
    }

// B-tiles loaded ONCE, consumed by both point-subsets. Per-point MFMA
// order identical to the proven R7 kernel (bit-identical results).
#define SPLIT_TILE2(accA, accB, hA0, hA1, lA0, lA1, hB0, hB1, lB0, lB1, OH, OL, row)              \
    {                                                                                             \
        const bf16x8 bh0 = *(const bf16x8*)&wsm[(OH) + (row) * SW + qd * 8];                      \
        const bf16x8 bh1 = *(const bf16x8*)&wsm[(OH) + (row) * SW + 32 + qd * 8];                 \
        accA = __builtin_amdgcn_mfma_f32_16x16x32_bf16(hA0, bh0, accA, 0, 0, 0);                  \
        accA = __builtin_amdgcn_mfma_f32_16x16x32_bf16(hA1, bh1, accA, 0, 0, 0);                  \
        accA = __builtin_amdgcn_mfma_f32_16x16x32_bf16(lA0, bh0, accA, 0, 0, 0);                  \
        accA = __builtin_amdgcn_mfma_f32_16x16x32_bf16(lA1, bh1, accA, 0, 0, 0);                  \
        accB = __builtin_amdgcn_mfma_f32_16x16x32_bf16(hB0, bh0, accB, 0, 0, 0);                  \
        accB = __builtin_amdgcn_mfma_f32_16x16x32_bf16(hB1, bh1, accB, 0, 0, 0);                  \
        accB = __builtin_amdgcn_mfma_f32_16x16x32_bf16(lB0, bh0, accB, 0, 0, 0);                  \
        accB = __builtin_amdgcn_mfma_f32_16x16x32_bf16(lB1, bh1, accB, 0, 0, 0);                  \
        const bf16x8 bl0 = *(const bf16x8*)&wsm[(OL) + (row) * SW + qd * 8];                      \
        const bf16x8 bl1 = *(const bf16x8*)&wsm[(OL) + (row) * SW + 32 + qd * 8];                 \
        accA = __builtin_amdgcn_mfma_f32_16x16x32_bf16(hA0, bl0, accA, 0, 0, 0);                  \
        accA = __builtin_amdgcn_mfma_f32_16x16x32_bf16(hA1, bl1, accA, 0, 0, 0);                  \
        accB = __builtin_amdgcn_mfma_f32_16x16x32_bf16(hB0, bl0, accB, 0, 0, 0);                  \
        accB = __builtin_amdgcn_mfma_f32_16x16x32_bf16(hB1, bl1, accB, 0, 0, 0);                  \
    }

    // ---- register prefetch of group 0's globals (both subsets) ----
    const int ptA0 = blockIdx.x * (GROUPS * 128) + wid * 32 + ln;
    unsigned int xuA0, xuA1, xuA2, xuA3, xuB0, xuB1, xuB2, xuB3;
    float dqA0, dqA1, dqA2, dqB0, dqB1, dqB2;
    xuA0 = wsp[(size_t)(qd * 4 + 0) * n + ptA0];
    xuA1 = wsp[(size_t)(qd * 4 + 1) * n + ptA0];
    xuA2 = wsp[(size_t)(qd * 4 + 2) * n + ptA0];
    xuA3 = wsp[(size_t)(qd * 4 + 3) * n + ptA0];
    xuB0 = wsp[(size_t)(qd * 4 + 0) * n + ptA0 + 16];
    xuB1 = wsp[(size_t)(qd * 4 + 1) * n + ptA0 + 16];
    xuB2 = wsp[(size_t)(qd * 4 + 2) * n + ptA0 + 16];
    xuB3 = wsp[(size_t)(qd * 4 + 3) * n + ptA0 + 16];
    dqA0 = dirp[3 * ptA0 + 0];
    dqA1 = dirp[3 * ptA0 + 1];
    dqA2 = dirp[3 * ptA0 + 2];
    dqB0 = dirp[3 * (ptA0 + 16) + 0];
    dqB1 = dirp[3 * (ptA0 + 16) + 1];
    dqB2 = dirp[3 * (ptA0 + 16) + 2];

#pragma unroll 1
    for (int grp = 0; grp < GROUPS; ++grp) {
        const int pt_base = blockIdx.x * (GROUPS * 128) + grp * 128 + wid * 32;
        const int pt = pt_base + ln;

        bf16x8 axA, axB;
        axA[0] = (short)(xuA0 & 0xffffu); axA[1] = (short)(xuA0 >> 16);
        axA[2] = (short)(xuA1 & 0xffffu); axA[3] = (short)(xuA1 >> 16);
        axA[4] = (short)(xuA2 & 0xffffu); axA[5] = (short)(xuA2 >> 16);
        axA[6] = (short)(xuA3 & 0xffffu); axA[7] = (short)(xuA3 >> 16);
        axB[0] = (short)(xuB0 & 0xffffu); axB[1] = (short)(xuB0 >> 16);
        axB[2] = (short)(xuB1 & 0xffffu); axB[3] = (short)(xuB1 >> 16);
        axB[4] = (short)(xuB2 & 0xffffu); axB[5] = (short)(xuB2 >> 16);
        axB[6] = (short)(xuB3 & 0xffffu); axB[7] = (short)(xuB3 >> 16);
        const float dAx = dqA0, dAy = dqA1, dAz = dqA2;
        const float dBx = dqB0, dBy = dqB1, dBz = dqB2;

        if (grp + 1 < GROUPS) {
            const int ptn = pt + 128;
            xuA0 = wsp[(size_t)(qd * 4 + 0) * n + ptn];
            xuA1 = wsp[(size_t)(qd * 4 + 1) * n + ptn];
            xuA2 = wsp[(size_t)(qd * 4 + 2) * n + ptn];
            xuA3 = wsp[(size_t)(qd * 4 + 3) * n + ptn];
            xuB0 = wsp[(size_t)(qd * 4 + 0) * n + ptn + 16];
            xuB1 = wsp[(size_t)(qd * 4 + 1) * n + ptn + 16];
            xuB2 = wsp[(size_t)(qd * 4 + 2) * n + ptn + 16];
            xuB3 = wsp[(size_t)(qd * 4 + 3) * n + ptn + 16];
            dqA0 = dirp[3 * ptn + 0];
            dqA1 = dirp[3 * ptn + 1];
            dqA2 = dirp[3 * ptn + 2];
            dqB0 = dirp[3 * (ptn + 16) + 0];
            dqB1 = dirp[3 * (ptn + 16) + 1];
            dqB2 = dirp[3 * (ptn + 16) + 2];
        }

        // ---- d1: Y = X @ Wd1 (single bf16), both subsets share B ----
#pragma unroll
        for (int t = 0; t < 4; ++t) {
            const bf16x8 b = *(const bf16x8*)&wsm[OW1 + (t * 16 + ln) * SW1 + qd * 8];
            const float bv = bd1v[t];
            f32x4 accA = {bv, bv, bv, bv};
            f32x4 accB = {bv, bv, bv, bv};
            accA = __builtin_amdgcn_mfma_f32_16x16x32_bf16(axA, b, accA, 0, 0, 0);
            accB = __builtin_amdgcn_mfma_f32_16x16x32_bf16(axB, b, accB, 0, 0, 0);
#pragma unroll
            for (int r = 0; r < 4; ++r) {
                A0[(qd * 4 + r) * SA + t * 16 + ln] = fmaxf(accA[r], 0.f);
                A1[(qd * 4 + r) * SA + t * 16 + ln] = fmaxf(accB[r], 0.f);
            }
        }

        // ---- d2: D = relu(Y) @ Wd2 (single bf16) ----
        {
            bf16x8 a0A, a1A, a0B, a1B;
#pragma unroll
            for (int j = 0; j < 8; ++j) a0A[j] = (short)f2bf(A0[ln * SA + qd * 8 + j]);
#pragma unroll
            for (int j = 0; j < 8; ++j) a1A[j] = (short)f2bf(A0[ln * SA + 32 + qd * 8 + j]);
#pragma unroll
            for (int j = 0; j < 8; ++j) a0B[j] = (short)f2bf(A1[ln * SA + qd * 8 + j]);
#pragma unroll
            for (int j = 0; j < 8; ++j) a1B[j] = (short)f2bf(A1[ln * SA + 32 + qd * 8 + j]);
            const bf16x8 b0 = *(const bf16x8*)&wsm[OW2 + ln * SW + qd * 8];
            const bf16x8 b1 = *(const bf16x8*)&wsm[OW2 + ln * SW + 32 + qd * 8];
            const float bv = bd2v;
            f32x4 accA = {bv, bv, bv, bv};
            f32x4 accB = {bv, bv, bv, bv};
            accA = __builtin_amdgcn_mfma_f32_16x16x32_bf16(a0A, b0, accA, 0, 0, 0);
            accA = __builtin_amdgcn_mfma_f32_16x16x32_bf16(a1A, b1, accA, 0, 0, 0);
            accB = __builtin_amdgcn_mfma_f32_16x16x32_bf16(a0B, b0, accB, 0, 0, 0);
            accB = __builtin_amdgcn_mfma_f32_16x16x32_bf16(a1B, b1, accB, 0, 0, 0);
            if (ln == 15) {
#pragma unroll
                for (int r = 0; r < 4; ++r) {
                    out[3 * n + pt_base + qd * 4 + r]      = fmaxf(accA[r], 0.f);
                    out[3 * n + pt_base + 16 + qd * 4 + r] = fmaxf(accB[r], 0.f);
                }
            }
#pragma unroll
            for (int r = 0; r < 4; ++r) {
                A0[(qd * 4 + r) * SA + ln] = accA[r];
                A1[(qd * 4 + r) * SA + ln] = accB[r];
            }
        }

        // ---- SH -> act fp32, k=16..40, per point ----
        SH_EMIT(&A0[ln * SA + 16], dAx, dAy, dAz)
        SH_EMIT(&A1[ln * SA + 16], dBx, dBy, dBz)

        // ---- c1: H1 = [D|SH|0] @ Wc1 (split), shared B ----
        {
            bf16x8 hA0, hA1, lA0, lA1, hB0, hB1, lB0, lB1;
            LOAD_SPLITP(A0, hA0, lA0, qd * 8)
            LOAD_SPLITP(A0, hA1, lA1, 32 + qd * 8)
            LOAD_SPLITP(A1, hB0, lB0, qd * 8)
            LOAD_SPLITP(A1, hB1, lB1, 32 + qd * 8)
#pragma unroll
            for (int t = 0; t < 4; ++t) {
                const float bv = bc1v[t];
                f32x4 accA = {bv, bv, bv, bv};
                f32x4 accB = {bv, bv, bv, bv};
                SPLIT_TILE2(accA, accB, hA0, hA1, lA0, lA1, hB0, hB1, lB0, lB1, OC1H, OC1L, t * 16 + ln)
#pragma unroll
                for (int r = 0; r < 4; ++r) {
                    A0[(qd * 4 + r) * SA + t * 16 + ln] = fmaxf(accA[r], 0.f);
                    A1[(qd * 4 + r) * SA + t * 16 + ln] = fmaxf(accB[r], 0.f);
                }
                __builtin_amdgcn_sched_barrier(0);
            }
        }

        // ---- c2: H2 = relu(H1) @ Wc2 (split), shared B ----
        {
            bf16x8 hA0, hA1, lA0, lA1, hB0, hB1, lB0, lB1;
            LOAD_SPLITP(A0, hA0, lA0, qd * 8)
            LOAD_SPLITP(A0, hA1, lA1, 32 + qd * 8)
            LOAD_SPLITP(A1, hB0, lB0, qd * 8)
            LOAD_SPLITP(A1, hB1, lB1, 32 + qd * 8)
#pragma unroll
            for (int t = 0; t < 4; ++t) {
                const float bv = bc2v[t];
                f32x4 accA = {bv, bv, bv, bv};
                f32x4 accB = {bv, bv, bv, bv};
                SPLIT_TILE2(accA, accB, hA0, hA1, lA0, lA1, hB0, hB1, lB0, lB1, OC2H, OC2L, t * 16 + ln)
#pragma unroll
                for (int r = 0; r < 4; ++r) {
                    A0[(qd * 4 + r) * SA + t * 16 + ln] = fmaxf(accA[r], 0.f);
                    A1[(qd * 4 + r) * SA + t * 16 + ln] = fmaxf(accB[r], 0.f);
                }
                __builtin_amdgcn_sched_barrier(0);
            }
        }

        // ---- c3 + sigmoid, shared B (rows 0-2 real, row 3 zero) ----
        {
            bf16x8 hA0, hA1, lA0, lA1, hB0, hB1, lB0, lB1;
            LOAD_SPLITP(A0, hA0, lA0, qd * 8)
            LOAD_SPLITP(A0, hA1, lA1, 32 + qd * 8)
            LOAD_SPLITP(A1, hB0, lB0, qd * 8)
            LOAD_SPLITP(A1, hB1, lB1, 32 + qd * 8)
            const float bv = bc3v;
            f32x4 accA = {bv, bv, bv, bv};
            f32x4 accB = {bv, bv, bv, bv};
            SPLIT_TILE2(accA, accB, hA0, hA1, lA0, lA1, hB0, hB1, lB0, lB1, OC3H, OC3L, (ln & 3))
            if (ln < 3) {
#pragma unroll
                for (int r = 0; r < 4; ++r) {
                    out[3 * (pt_base + qd * 4 + r) + ln]      = 1.f / (1.f + expf(-accA[r]));
                    out[3 * (pt_base + 16 + qd * 4 + r) + ln] = 1.f / (1.f + expf(-accB[r]));
                }
            }
        }
    }
}

// ------------------------------------------------------------------
// Fallback: round-1 fused kernel (if ws too small / n not 2^19) — proven
// ------------------------------------------------------------------
__global__ __launch_bounds__(256)
void nerf_fused(const float* __restrict__ pos,
                const float* __restrict__ dirp,
                const float* __restrict__ tables,
                const float* __restrict__ Wd1, const float* __restrict__ bd1,
                const float* __restrict__ Wd2, const float* __restrict__ bd2,
                const float* __restrict__ Wc1, const float* __restrict__ bc1,
                const float* __restrict__ Wc2, const float* __restrict__ bc2,
                const float* __restrict__ Wc3, const float* __restrict__ bc3,
                float* __restrict__ out, int n)
{
    const int idx = blockIdx.x * blockDim.x + threadIdx.x;
    if (idx >= n) return;
    const float px = pos[3 * idx + 0], py = pos[3 * idx + 1], pz = pos[3 * idx + 2];
    float y[64];
#pragma unroll
    for (int j = 0; j < 64; ++j) y[j] = bd1[j];
#pragma unroll
    for (int l = 0; l < LEVELS; ++l) {
        const float resf = (float)(16 << l);
        const float tx = px * resf, ty = py * resf, tz = pz * resf;
        const float fx = floorf(tx), fy = floorf(ty), fz = floorf(tz);
        const float wx = tx - fx, wy = ty - fy, wz = tz - fz;
        const unsigned ix = (unsigned)(int)fx, iy = (unsigned)(int)fy, iz = (unsigned)(int)fz;
        const unsigned hy0 = iy * 2654435761u, hy1 = hy0 + 2654435761u;
        const unsigned hz0 = iz * 805459861u,  hz1 = hz0 + 805459861u;
        const unsigned ix1 = ix + 1u;
        const float2* tb = (const float2*)tables + (size_t)l * TBL;
        const float2 e000 = tb[(ix  ^ hy0 ^ hz0) & TMASK];
        const float2 e001 = tb[(ix  ^ hy0 ^ hz1) & TMASK];
        const float2 e010 = tb[(ix  ^ hy1 ^ hz0) & TMASK];
        const float2 e011 = tb[(ix  ^ hy1 ^ hz1) & TMASK];
        const float2 e100 = tb[(ix1 ^ hy0 ^ hz0) & TMASK];
        const float2 e101 = tb[(ix1 ^ hy0 ^ hz1) & TMASK];
        const float2 e110 = tb[(ix1 ^ hy1 ^ hz0) & TMASK];
        const float2 e111 = tb[(ix1 ^ hy1 ^ hz1) & TMASK];
        const float ux = 1.f - wx, uy = 1.f - wy, uz = 1.f - wz;
        const float c000 = ux*uy*uz, c001 = ux*uy*wz, c010 = ux*wy*uz, c011 = ux*wy*wz;
        const float c100 = wx*uy*uz, c101 = wx*uy*wz, c110 = wx*wy*uz, c111 = wx*wy*wz;
        float f0 = e000.x*c000, f1 = e000.y*c000;
        f0 = fmaf(e001.x,c001,f0); f1 = fmaf(e001.y,c001,f1);
        f0 = fmaf(e010.x,c010,f0); f1 = fmaf(e010.y,c010,f1);
        f0 = fmaf(e011.x,c011,f0); f1 = fmaf(e011.y,c011,f1);
        f0 = fmaf(e100.x,c100,f0); f1 = fmaf(e100.y,c100,f1);
        f0 = fmaf(e101.x,c101,f0); f1 = fmaf(e101.y,c101,f1);
        f0 = fmaf(e110.x,c110,f0); f1 = fmaf(e110.y,c110,f1);
        f0 = fmaf(e111.x,c111,f0); f1 = fmaf(e111.y,c111,f1);
        const float* w0 = Wd1 + (size_t)(2 * l) * 64;
#pragma unroll
        for (int j = 0; j < 64; ++j)
            y[j] = fmaf(f0, w0[j], fmaf(f1, w0[64 + j], y[j]));
    }
    float d[16];
#pragma unroll
    for (int k = 0; k < 16; ++k) d[k] = bd2[k];
#pragma unroll
    for (int j = 0; j < 64; ++j) {
        const float a = fmaxf(y[j], 0.f);
#pragma unroll
        for (int k = 0; k < 16; ++k) d[k] = fmaf(a, Wd2[j * 16 + k], d[k]);
    }
    out[3 * n + idx] = fmaxf(d[15], 0.f);
    const float dx = dirp[3*idx], dy = dirp[3*idx+1], dz = dirp[3*idx+2];
    float sh[25];
    SH_BLOCK(sh, dx, dy, dz)
    float h1[64];
#pragma unroll
    for (int j = 0; j < 64; ++j) h1[j] = bc1[j];
#pragma unroll
    for (int i = 0; i < 16; ++i) {
#pragma unroll
        for (int j = 0; j < 64; ++j) h1[j] = fmaf(d[i], Wc1[i * 64 + j], h1[j]);
    }
#pragma unroll
    for (int s = 0; s < 25; ++s) {
#pragma unroll
        for (int j = 0; j < 64; ++j) h1[j] = fmaf(sh[s], Wc1[(16 + s) * 64 + j], h1[j]);
    }
    float h2[64];
#pragma unroll
    for (int j = 0; j < 64; ++j) h2[j] = bc2[j];
#pragma unroll
    for (int i = 0; i < 64; ++i) {
        const float a = fmaxf(h1[i], 0.f);
#pragma unroll
        for (int j = 0; j < 64; ++j) h2[j] = fmaf(a, Wc2[i * 64 + j], h2[j]);
    }
    float r0 = bc3[0], r1 = bc3[1], r2 = bc3[2];
#pragma unroll
    for (int j = 0; j < 64; ++j) {
        const float a = fmaxf(h2[j], 0.f);
        r0 = fmaf(a, Wc3[j * 3 + 0], r0);
        r1 = fmaf(a, Wc3[j * 3 + 1], r1);
        r2 = fmaf(a, Wc3[j * 3 + 2], r2);
    }
    out[3 * idx + 0] = 1.f / (1.f + expf(-r0));
    out[3 * idx + 1] = 1.f / (1.f + expf(-r1));
    out[3 * idx + 2] = 1.f / (1.f + expf(-r2));
}

extern "C" void kernel_launch(void* const* d_in, const int* in_sizes, int n_in,
                              void* d_out, int out_size, void* d_ws, size_t ws_size,
                              hipStream_t stream) {
    const float* pos    = (const float*)d_in[0];
    const float* dir    = (const float*)d_in[1];
    const float* tables = (const float*)d_in[2];
    const float* Wd1 = (const float*)d_in[3];
    const float* bd1 = (const float*)d_in[4];
    const float* Wd2 = (const float*)d_in[5];
    const float* bd2 = (const float*)d_in[6];
    const float* Wc1 = (const float*)d_in[7];
    const float* bc1 = (const float*)d_in[8];
    const float* Wc2 = (const float*)d_in[9];
    const float* bc2 = (const float*)d_in[10];
    const float* Wc3 = (const float*)d_in[11];
    const float* bc3 = (const float*)d_in[12];

    const int n = in_sizes[0] / 3;
    const int blocks = (n + 255) / 256;

    // workspace layout: [0, n*64) packed-bf16 feature planes;
    //                   [n*64, n*128) packed-bf16 tables (16*TBL uints)
    if (ws_size >= (size_t)n * 128 && n == 524288) {
        unsigned int* wsp  = (unsigned int*)d_ws;
        unsigned int* tb16 = (unsigned int*)((char*)d_ws + (size_t)n * 64);
        const int total = LEVELS * TBL;
        cvt_tables<<<total / 1024, 256, 0, stream>>>(tables, tb16, total);
        ngp_encode_lvl<<<8 * blocks, 256, 0, stream>>>(pos, tb16, wsp, n, 0);
        ngp_encode_lvl<<<8 * blocks, 256, 0, stream>>>(pos, tb16, wsp, n, 8);
        ngp_mlp_mfma4<<<n / (GROUPS * 128), 256, 0, stream>>>((const unsigned int*)wsp, dir,
                                                              Wd1, bd1, Wd2, bd2,
                                                              Wc1, bc1, Wc2, bc2, Wc3, bc3,
                                                              (float*)d_out, n);
    } else {
        nerf_fused<<<blocks, 256, 0, stream>>>(pos, dir, tables,
                                               Wd1, bd1, Wd2, bd2,
                                               Wc1, bc1, Wc2, bc2, Wc3, bc3,
                                               (float*)d_out, n);
    }
}

// Round 10
// 352.807 us; speedup vs baseline: 1.2192x; 1.0069x over previous
//
#include <hip/hip_runtime.h>
#include <math.h>

#define LEVELS 16
#define TBL 524288          // 2^19 entries per level
#define TMASK (TBL - 1)

typedef short bf16x8 __attribute__((ext_vector_type(8)));
typedef float f32x4  __attribute__((ext_vector_type(4)));
typedef float fvec4  __attribute__((ext_vector_type(4)));
typedef unsigned int uvec4 __attribute__((ext_vector_type(4)));

static __device__ __forceinline__ unsigned short f2bf(float x) {
    unsigned u = __float_as_uint(x);
    u += 0x7fffu + ((u >> 16) & 1u);    // RNE
    return (unsigned short)(u >> 16);
}
static __device__ __forceinline__ float b2f(unsigned short h) {
    return __uint_as_float(((unsigned)h) << 16);
}

// SH degree-4 block, constants computed exactly as round-1 (verified correct).
#define SH_BLOCK(sh, dx, dy, dz)                                                          \
    const float x2 = dx * dx, y2 = dy * dy, z2 = dz * dz;                                 \
    const float xy = dx * dy, xz = dx * dz, yz = dy * dz;                                 \
    const float x4 = x2 * x2, y4 = y2 * y2;                                               \
    const float c0  = (float)(0.5 * sqrt(1.0 / M_PI));                                    \
    const float c1  = (float)(0.5 * sqrt(3.0 / M_PI));                                    \
    const float sub = (float)(0.25 * sqrt(5.0 / M_PI));                                   \
    const float v1  = (float)(0.25 * sqrt(15.0 / M_PI));                                  \
    const float v2  = (float)(0.5 * sqrt(15.0 / M_PI));                                   \
    const float v3  = (float)(0.75 * sqrt(5.0 / M_PI));                                   \
    const float w1c = (float)(0.25 * sqrt(105.0 / M_PI));                                 \
    const float w2c = (float)(0.5 * sqrt(105.0 / M_PI));                                  \
    const float w3c = (float)(0.25 * sqrt(35.0 / (2.0 * M_PI)));                          \
    const float w4c = (float)(0.5 * sqrt(7.0 / (6.0 * M_PI)));                            \
    sh[0] = c0;                                                                           \
    sh[1] = -c1 * dy;                                                                     \
    sh[2] =  c1 * dz;                                                                     \
    sh[3] = -c1 * dx;                                                                     \
    sh[4] =  v2 * xy;                                                                     \
    sh[5] = -v2 * yz;                                                                     \
    sh[6] =  v3 * z2 - sub;                                                               \
    sh[7] = -v2 * xz;                                                                     \
    sh[8] =  v1 * x2 - v1 * y2;                                                           \
    sh[9]  = -w3c * dy * (3.0f * x2 - y2);                                                \
    sh[10] =  w2c * xy * dz;                                                              \
    sh[11] =  w4c * dy * (1.5f - 7.5f * z2);                                              \
    sh[12] =  1.24392110863372f * dz * (1.5f * z2 - 0.5f) - 0.497568443453487f * dz;      \
    sh[13] =  w4c * dx * (1.5f - 7.5f * z2);                                              \
    sh[14] =  w1c * dz * (x2 - y2);                                                       \
    sh[15] = -w3c * dx * (x2 - 3.0f * y2);                                                \
    sh[16] =  2.5033429417967f * xy * (x2 - y2);                                          \
    sh[17] = -1.77013076977993f * yz * (3.0f * x2 - y2);                                  \
    sh[18] =  0.126156626101008f * xy * (52.5f * z2 - 7.5f);                              \
    sh[19] =  0.267618617422916f * dy * (2.33333333333333f * dz * (1.5f - 7.5f * z2) + 4.0f * dz); \
    sh[20] =  1.48099765681286f * dz * (1.66666666666667f * dz * (1.5f * z2 - 0.5f) - 0.666666666666667f * dz) \
              - 0.952069922236839f * z2 + 0.317356640745613f;                             \
    sh[21] =  0.267618617422916f * dx * (2.33333333333333f * dz * (1.5f - 7.5f * z2) + 4.0f * dz); \
    sh[22] =  0.063078313050504f * (x2 - y2) * (52.5f * z2 - 7.5f);                       \
    sh[23] = -1.77013076977993f * xz * (x2 - 3.0f * y2);                                  \
    sh[24] = -3.75501441269506f * x2 * y2 + 0.625835735449176f * x4 + 0.625835735449176f * y4;

// Per-point SH emit into an act row pointer, predicated by qd (bit-identical exprs).
#define SH_EMIT(Ash, DXV, DYV, DZV)                                                        \
    {                                                                                      \
        const float sx2 = (DXV)*(DXV), sy2 = (DYV)*(DYV), sz2 = (DZV)*(DZV);               \
        const float sxy = (DXV)*(DYV), sxz = (DXV)*(DZV), syz = (DYV)*(DZV);               \
        const float sx4 = sx2*sx2, sy4 = sy2*sy2;                                          \
        const float k0  = (float)(0.5 * sqrt(1.0 / M_PI));                                 \
        const float k1  = (float)(0.5 * sqrt(3.0 / M_PI));                                 \
        const float ksub= (float)(0.25 * sqrt(5.0 / M_PI));                                \
        const float kv1 = (float)(0.25 * sqrt(15.0 / M_PI));                               \
        const float kv2 = (float)(0.5 * sqrt(15.0 / M_PI));                                \
        const float kv3 = (float)(0.75 * sqrt(5.0 / M_PI));                                \
        const float kw1 = (float)(0.25 * sqrt(105.0 / M_PI));                              \
        const float kw2 = (float)(0.5 * sqrt(105.0 / M_PI));                               \
        const float kw3 = (float)(0.25 * sqrt(35.0 / (2.0 * M_PI)));                       \
        const float kw4 = (float)(0.5 * sqrt(7.0 / (6.0 * M_PI)));                         \
        if ((0  & 3) == qd) (Ash)[0]  = k0;                                                \
        if ((1  & 3) == qd) (Ash)[1]  = -k1 * (DYV);                                       \
        if ((2  & 3) == qd) (Ash)[2]  =  k1 * (DZV);                                       \
        if ((3  & 3) == qd) (Ash)[3]  = -k1 * (DXV);                                       \
        if ((4  & 3) == qd) (Ash)[4]  =  kv2 * sxy;                                        \
        if ((5  & 3) == qd) (Ash)[5]  = -kv2 * syz;                                        \
        if ((6  & 3) == qd) (Ash)[6]  =  kv3 * sz2 - ksub;                                 \
        if ((7  & 3) == qd) (Ash)[7]  = -kv2 * sxz;                                        \
        if ((8  & 3) == qd) (Ash)[8]  =  kv1 * sx2 - kv1 * sy2;                            \
        if ((9  & 3) == qd) (Ash)[9]  = -kw3 * (DYV) * (3.0f * sx2 - sy2);                 \
        if ((10 & 3) == qd) (Ash)[10] =  kw2 * sxy * (DZV);                                \
        if ((11 & 3) == qd) (Ash)[11] =  kw4 * (DYV) * (1.5f - 7.5f * sz2);                \
        if ((12 & 3) == qd) (Ash)[12] =  1.24392110863372f * (DZV) * (1.5f * sz2 - 0.5f) - 0.497568443453487f * (DZV); \
        if ((13 & 3) == qd) (Ash)[13] =  kw4 * (DXV) * (1.5f - 7.5f * sz2);                \
        if ((14 & 3) == qd) (Ash)[14] =  kw1 * (DZV) * (sx2 - sy2);                        \
        if ((15 & 3) == qd) (Ash)[15] = -kw3 * (DXV) * (sx2 - 3.0f * sy2);                 \
        if ((16 & 3) == qd) (Ash)[16] =  2.5033429417967f * sxy * (sx2 - sy2);             \
        if ((17 & 3) == qd) (Ash)[17] = -1.77013076977993f * syz * (3.0f * sx2 - sy2);     \
        if ((18 & 3) == qd) (Ash)[18] =  0.126156626101008f * sxy * (52.5f * sz2 - 7.5f);  \
        if ((19 & 3) == qd) (Ash)[19] =  0.267618617422916f * (DYV) * (2.33333333333333f * (DZV) * (1.5f - 7.5f * sz2) + 4.0f * (DZV)); \
        if ((20 & 3) == qd) (Ash)[20] =  1.48099765681286f * (DZV) * (1.66666666666667f * (DZV) * (1.5f * sz2 - 0.5f) - 0.666666666666667f * (DZV)) \
                                         - 0.952069922236839f * sz2 + 0.317356640745613f;  \
        if ((21 & 3) == qd) (Ash)[21] =  0.267618617422916f * (DXV) * (2.33333333333333f * (DZV) * (1.5f - 7.5f * sz2) + 4.0f * (DZV)); \
        if ((22 & 3) == qd) (Ash)[22] =  0.063078313050504f * (sx2 - sy2) * (52.5f * sz2 - 7.5f); \
        if ((23 & 3) == qd) (Ash)[23] = -1.77013076977993f * sxz * (sx2 - 3.0f * sy2);     \
        if ((24 & 3) == qd) (Ash)[24] = -3.75501441269506f * sx2 * sy2 + 0.625835735449176f * sx4 + 0.625835735449176f * sy4; \
    }

// ------------------------------------------------------------------
// Kernel 0: pack fp32 tables -> bf16x2 (one uint per entry).
// ------------------------------------------------------------------
__global__ __launch_bounds__(256)
void cvt_tables(const float* __restrict__ tables,
                unsigned int* __restrict__ tb16, int total)
{
    const int i = (blockIdx.x * 256 + threadIdx.x) * 4;   // 4 entries/thread
    if (i >= total) return;
    const fvec4 a = __builtin_nontemporal_load((const fvec4*)(tables + 2 * (size_t)i));
    const fvec4 b = __builtin_nontemporal_load((const fvec4*)(tables + 2 * (size_t)i) + 1);
    uvec4 o;
    o.x = ((unsigned)f2bf(a.y) << 16) | f2bf(a.x);
    o.y = ((unsigned)f2bf(a.w) << 16) | f2bf(a.z);
    o.z = ((unsigned)f2bf(b.y) << 16) | f2bf(b.x);
    o.w = ((unsigned)f2bf(b.w) << 16) | f2bf(b.z);
    __builtin_nontemporal_store(o, (uvec4*)&tb16[i]);
}

// ------------------------------------------------------------------
// Kernel 1: hash-grid gather, HALF the levels per dispatch (R19).
// l = lbase + (b&7): one 2 MB table per XCD L2. Launched twice.
// ------------------------------------------------------------------
__global__ __launch_bounds__(256)
void ngp_encode_lvl(const float* __restrict__ pos,
                    const unsigned int* __restrict__ tb16,
                    unsigned int* __restrict__ wsp, int n, int lbase)
{
    const int b = blockIdx.x;
    const int l = lbase + (b & 7);
    const int c = b >> 3;
    const int idx = c * 256 + threadIdx.x;
    if (idx >= n || l >= LEVELS) return;

    const float px = pos[3 * idx + 0];
    const float py = pos[3 * idx + 1];
    const float pz = pos[3 * idx + 2];

    const float resf = (float)(16 << l);
    const float tx = px * resf, ty = py * resf, tz = pz * resf;
    const float fx = floorf(tx), fy = floorf(ty), fz = floorf(tz);
    const float wx = tx - fx, wy = ty - fy, wz = tz - fz;
    const unsigned ix = (unsigned)(int)fx;
    const unsigned iy = (unsigned)(int)fy;
    const unsigned iz = (unsigned)(int)fz;
    const unsigned hy0 = iy * 2654435761u, hy1 = hy0 + 2654435761u;
    const unsigned hz0 = iz * 805459861u,  hz1 = hz0 + 805459861u;
    const unsigned ix1 = ix + 1u;

    const unsigned int* tb = tb16 + (size_t)l * TBL;
    const unsigned hA = hy0 ^ hz0;        // (y=0,z=0)
    const unsigned hB = hy0 ^ hz1;        // (y=0,z=1)
    const unsigned hC = hy1 ^ hz0;        // (y=1,z=0)
    const unsigned hD = hy1 ^ hz1;        // (y=1,z=1)

    unsigned eA0, eA1, eB0, eB1, eC0, eC1, eD0, eD1;   // e{combo}{x}
    if ((ix & 1u) == 0u) {
        // even ix: {ix^h, (ix+1)^h} = {m, m^1} -> one aligned 8B load
        const uint2 pA = *(const uint2*)&tb[((ix ^ hA) & TMASK) & ~1u];
        const uint2 pB = *(const uint2*)&tb[((ix ^ hB) & TMASK) & ~1u];
        const uint2 pC = *(const uint2*)&tb[((ix ^ hC) & TMASK) & ~1u];
        const uint2 pD = *(const uint2*)&tb[((ix ^ hD) & TMASK) & ~1u];
        const unsigned sA = hA & 1u, sB = hB & 1u, sC = hC & 1u, sD = hD & 1u;
        eA0 = sA ? pA.y : pA.x;  eA1 = sA ? pA.x : pA.y;
        eB0 = sB ? pB.y : pB.x;  eB1 = sB ? pB.x : pB.y;
        eC0 = sC ? pC.y : pC.x;  eC1 = sC ? pC.x : pC.y;
        eD0 = sD ? pD.y : pD.x;  eD1 = sD ? pD.x : pD.y;
    } else {
        eA0 = tb[(ix  ^ hA) & TMASK];  eA1 = tb[(ix1 ^ hA) & TMASK];
        eB0 = tb[(ix  ^ hB) & TMASK];  eB1 = tb[(ix1 ^ hB) & TMASK];
        eC0 = tb[(ix  ^ hC) & TMASK];  eC1 = tb[(ix1 ^ hC) & TMASK];
        eD0 = tb[(ix  ^ hD) & TMASK];  eD1 = tb[(ix1 ^ hD) & TMASK];
    }

#define UNPX(e) __uint_as_float((e) << 16)
#define UNPY(e) __uint_as_float((e) & 0xffff0000u)

    const float ux = 1.f - wx, uy = 1.f - wy, uz = 1.f - wz;
    const float c000 = ux * uy * uz, c001 = ux * uy * wz;
    const float c010 = ux * wy * uz, c011 = ux * wy * wz;
    const float c100 = wx * uy * uz, c101 = wx * uy * wz;
    const float c110 = wx * wy * uz, c111 = wx * wy * wz;

    float f0 = UNPX(eA0) * c000, f1 = UNPY(eA0) * c000;
    f0 = fmaf(UNPX(eB0), c001, f0); f1 = fmaf(UNPY(eB0), c001, f1);
    f0 = fmaf(UNPX(eC0), c010, f0); f1 = fmaf(UNPY(eC0), c010, f1);
    f0 = fmaf(UNPX(eD0), c011, f0); f1 = fmaf(UNPY(eD0), c011, f1);
    f0 = fmaf(UNPX(eA1), c100, f0); f1 = fmaf(UNPY(eA1), c100, f1);
    f0 = fmaf(UNPX(eB1), c101, f0); f1 = fmaf(UNPY(eB1), c101, f1);
    f0 = fmaf(UNPX(eC1), c110, f0); f1 = fmaf(UNPY(eC1), c110, f1);
    f0 = fmaf(UNPX(eD1), c111, f0); f1 = fmaf(UNPY(eD1), c111, f1);

    const unsigned int h0 = f2bf(f0);
    const unsigned int h1 = f2bf(f1);
    __builtin_nontemporal_store((h1 << 16) | h0, &wsp[(size_t)l * n + idx]);
}

// ------------------------------------------------------------------
// Kernel 2 (R20): split-precision MFMA MLP, 32 points per wave-iter.
// R20: sched_barrier(0) calls REMOVED. They were added in R17 to stop
// B-tile hoisting at the (512,4)=128-VGPR cap; at the current (256,2)
// =256 cap with only 104 VGPR used and LDS-limited occupancy (2 waves
// /SIMD), VGPRs are free — the barriers only forbade the scheduler
// from pipelining the 4 t-iterations' dependent MFMA chains (R19
// counters: MfmaUtil 11.8%, VALU 39%, occupancy at its 25% cap but
// dur stuck at 110 us = serial-chain-bound, not wave-count-bound).
// If FETCH/WRITE inflate symmetrically next round, it spilled ->
// re-add. Everything else identical to R19 (bit-identical).
// ------------------------------------------------------------------
#define GROUPS 8
#define SW1  32                  // Wd1 k-stride (shorts), rows 16B-aligned
#define SW   72                  // 64-k weight stride (shorts), rows 16B-aligned
#define SA   68                  // act k-stride (floats); 272B rows, 16B-aligned
#define OW1  0                   // 64*32 = 2048
#define OW2  2048                // 16*72 = 1152
#define OC1H 3200                // 64*72 = 4608
#define OC1L 7808
#define OC2H 12416
#define OC2L 17024
#define OC3H 21632               // 4*72 = 288 (rows 0-2 real, row 3 zero)
#define OC3L 21920
#define WTOT 22208               // shorts = 44,416 B; + act 34,816 B = 79,232 B

__global__ __launch_bounds__(256, 2)
void ngp_mlp_mfma4(const unsigned int* __restrict__ wsp,
                   const float* __restrict__ dirp,
                   const float* __restrict__ Wd1, const float* __restrict__ bd1,
                   const float* __restrict__ Wd2, const float* __restrict__ bd2,
                   const float* __restrict__ Wc1, const float* __restrict__ bc1,
                   const float* __restrict__ Wc2, const float* __restrict__ bc2,
                   const float* __restrict__ Wc3, const float* __restrict__ bc3,
                   float* __restrict__ out, int n)
{
    __shared__ short wsm[WTOT];
    __shared__ float act[4 * 32 * SA];     // 34,816 B
    const int tid = threadIdx.x;

    for (int t = tid; t < WTOT; t += 256) wsm[t] = 0;
    __syncthreads();

    for (int g = tid; g < 32 * 64; g += 256) {            // Wd1 (32,64) single
        const int k = g >> 6, nn = g & 63;
        wsm[OW1 + nn * SW1 + k] = f2bf(Wd1[g]);
    }
    for (int g = tid; g < 64 * 16; g += 256) {            // Wd2 (64,16) single
        const int k = g >> 4, nn = g & 15;
        wsm[OW2 + nn * SW + k] = f2bf(Wd2[g]);
    }
    for (int g = tid; g < 41 * 64; g += 256) {            // Wc1 (41,64) hi+lo
        const int k = g >> 6, nn = g & 63;
        const float w = Wc1[g];
        const unsigned short hh = f2bf(w);
        wsm[OC1H + nn * SW + k] = hh;
        wsm[OC1L + nn * SW + k] = f2bf(w - b2f(hh));
    }
    for (int g = tid; g < 64 * 64; g += 256) {            // Wc2 (64,64) hi+lo
        const int k = g >> 6, nn = g & 63;
        const float w = Wc2[g];
        const unsigned short hh = f2bf(w);
        wsm[OC2H + nn * SW + k] = hh;
        wsm[OC2L + nn * SW + k] = f2bf(w - b2f(hh));
    }
    for (int g = tid; g < 64 * 3; g += 256) {             // Wc3 (64,3) hi+lo
        const int k = g / 3, nn = g - 3 * k;
        const float w = Wc3[g];
        const unsigned short hh = f2bf(w);
        wsm[OC3H + nn * SW + k] = hh;
        wsm[OC3L + nn * SW + k] = f2bf(w - b2f(hh));
    }
    __syncthreads();

    const int wid = tid >> 6;              // 0..3
    const int lane = tid & 63;
    const int ln = lane & 15;
    const int qd = lane >> 4;
    float* A0 = act + wid * (32 * SA);     // rows 0-15: sub0
    float* A1 = A0 + 16 * SA;              // rows 16-31: sub1

    float bd1v[4], bc1v[4], bc2v[4];
#pragma unroll
    for (int t = 0; t < 4; ++t) {
        bd1v[t] = bd1[t * 16 + ln];
        bc1v[t] = bc1[t * 16 + ln];
        bc2v[t] = bc2[t * 16 + ln];
    }
    const float bd2v = bd2[ln];
    const float bc3v = (ln < 3) ? bc3[ln] : 0.f;

#define LOAD_SPLITP(AP, ah, al, k0)                              \
    {                                                            \
        _Pragma("unroll")                                        \
        for (int j = 0; j < 8; ++j) {                            \
            const float v = (AP)[ln * SA + (k0) + j];            \
            const unsigned short hb = f2bf(v);                   \
            ah[j] = (short)hb;                                   \
            al[j] = (short)f2bf(v - b2f(hb));                    \
        }                                                        \
    }

// B-tiles loaded ONCE, consumed by both point-subsets. Per-point MFMA
// order identical to the proven R7 kernel (bit-identical results).
#define SPLIT_TILE2(accA, accB, hA0, hA1, lA0, lA1, hB0, hB1, lB0, lB1, OH, OL, row)              \
    {                                                                                             \
        const bf16x8 bh0 = *(const bf16x8*)&wsm[(OH) + (row) * SW + qd * 8];                      \
        const bf16x8 bh1 = *(const bf16x8*)&wsm[(OH) + (row) * SW + 32 + qd * 8];                 \
        accA = __builtin_amdgcn_mfma_f32_16x16x32_bf16(hA0, bh0, accA, 0, 0, 0);                  \
        accA = __builtin_amdgcn_mfma_f32_16x16x32_bf16(hA1, bh1, accA, 0, 0, 0);                  \
        accA = __builtin_amdgcn_mfma_f32_16x16x32_bf16(lA0, bh0, accA, 0, 0, 0);                  \
        accA = __builtin_amdgcn_mfma_f32_16x16x32_bf16(lA1, bh1, accA, 0, 0, 0);                  \
        accB = __builtin_amdgcn_mfma_f32_16x16x32_bf16(hB0, bh0, accB, 0, 0, 0);                  \
        accB = __builtin_amdgcn_mfma_f32_16x16x32_bf16(hB1, bh1, accB, 0, 0, 0);                  \
        accB = __builtin_amdgcn_mfma_f32_16x16x32_bf16(lB0, bh0, accB, 0, 0, 0);                  \
        accB = __builtin_amdgcn_mfma_f32_16x16x32_bf16(lB1, bh1, accB, 0, 0, 0);                  \
        const bf16x8 bl0 = *(const bf16x8*)&wsm[(OL) + (row) * SW + qd * 8];                      \
        const bf16x8 bl1 = *(const bf16x8*)&wsm[(OL) + (row) * SW + 32 + qd * 8];                 \
        accA = __builtin_amdgcn_mfma_f32_16x16x32_bf16(hA0, bl0, accA, 0, 0, 0);                  \
        accA = __builtin_amdgcn_mfma_f32_16x16x32_bf16(hA1, bl1, accA, 0, 0, 0);                  \
        accB = __builtin_amdgcn_mfma_f32_16x16x32_bf16(hB0, bl0, accB, 0, 0, 0);                  \
        accB = __builtin_amdgcn_mfma_f32_16x16x32_bf16(hB1, bl1, accB, 0, 0, 0);                  \
    }

    // ---- register prefetch of group 0's globals (both subsets) ----
    const int ptA0 = blockIdx.x * (GROUPS * 128) + wid * 32 + ln;
    unsigned int xuA0, xuA1, xuA2, xuA3, xuB0, xuB1, xuB2, xuB3;
    float dqA0, dqA1, dqA2, dqB0, dqB1, dqB2;
    xuA0 = wsp[(size_t)(qd * 4 + 0) * n + ptA0];
    xuA1 = wsp[(size_t)(qd * 4 + 1) * n + ptA0];
    xuA2 = wsp[(size_t)(qd * 4 + 2) * n + ptA0];
    xuA3 = wsp[(size_t)(qd * 4 + 3) * n + ptA0];
    xuB0 = wsp[(size_t)(qd * 4 + 0) * n + ptA0 + 16];
    xuB1 = wsp[(size_t)(qd * 4 + 1) * n + ptA0 + 16];
    xuB2 = wsp[(size_t)(qd * 4 + 2) * n + ptA0 + 16];
    xuB3 = wsp[(size_t)(qd * 4 + 3) * n + ptA0 + 16];
    dqA0 = dirp[3 * ptA0 + 0];
    dqA1 = dirp[3 * ptA0 + 1];
    dqA2 = dirp[3 * ptA0 + 2];
    dqB0 = dirp[3 * (ptA0 + 16) + 0];
    dqB1 = dirp[3 * (ptA0 + 16) + 1];
    dqB2 = dirp[3 * (ptA0 + 16) + 2];

#pragma unroll 1
    for (int grp = 0; grp < GROUPS; ++grp) {
        const int pt_base = blockIdx.x * (GROUPS * 128) + grp * 128 + wid * 32;
        const int pt = pt_base + ln;

        bf16x8 axA, axB;
        axA[0] = (short)(xuA0 & 0xffffu); axA[1] = (short)(xuA0 >> 16);
        axA[2] = (short)(xuA1 & 0xffffu); axA[3] = (short)(xuA1 >> 16);
        axA[4] = (short)(xuA2 & 0xffffu); axA[5] = (short)(xuA2 >> 16);
        axA[6] = (short)(xuA3 & 0xffffu); axA[7] = (short)(xuA3 >> 16);
        axB[0] = (short)(xuB0 & 0xffffu); axB[1] = (short)(xuB0 >> 16);
        axB[2] = (short)(xuB1 & 0xffffu); axB[3] = (short)(xuB1 >> 16);
        axB[4] = (short)(xuB2 & 0xffffu); axB[5] = (short)(xuB2 >> 16);
        axB[6] = (short)(xuB3 & 0xffffu); axB[7] = (short)(xuB3 >> 16);
        const float dAx = dqA0, dAy = dqA1, dAz = dqA2;
        const float dBx = dqB0, dBy = dqB1, dBz = dqB2;

        if (grp + 1 < GROUPS) {
            const int ptn = pt + 128;
            xuA0 = wsp[(size_t)(qd * 4 + 0) * n + ptn];
            xuA1 = wsp[(size_t)(qd * 4 + 1) * n + ptn];
            xuA2 = wsp[(size_t)(qd * 4 + 2) * n + ptn];
            xuA3 = wsp[(size_t)(qd * 4 + 3) * n + ptn];
            xuB0 = wsp[(size_t)(qd * 4 + 0) * n + ptn + 16];
            xuB1 = wsp[(size_t)(qd * 4 + 1) * n + ptn + 16];
            xuB2 = wsp[(size_t)(qd * 4 + 2) * n + ptn + 16];
            xuB3 = wsp[(size_t)(qd * 4 + 3) * n + ptn + 16];
            dqA0 = dirp[3 * ptn + 0];
            dqA1 = dirp[3 * ptn + 1];
            dqA2 = dirp[3 * ptn + 2];
            dqB0 = dirp[3 * (ptn + 16) + 0];
            dqB1 = dirp[3 * (ptn + 16) + 1];
            dqB2 = dirp[3 * (ptn + 16) + 2];
        }

        // ---- d1: Y = X @ Wd1 (single bf16), both subsets share B ----
#pragma unroll
        for (int t = 0; t < 4; ++t) {
            const bf16x8 b = *(const bf16x8*)&wsm[OW1 + (t * 16 + ln) * SW1 + qd * 8];
            const float bv = bd1v[t];
            f32x4 accA = {bv, bv, bv, bv};
            f32x4 accB = {bv, bv, bv, bv};
            accA = __builtin_amdgcn_mfma_f32_16x16x32_bf16(axA, b, accA, 0, 0, 0);
            accB = __builtin_amdgcn_mfma_f32_16x16x32_bf16(axB, b, accB, 0, 0, 0);
#pragma unroll
            for (int r = 0; r < 4; ++r) {
                A0[(qd * 4 + r) * SA + t * 16 + ln] = fmaxf(accA[r], 0.f);
                A1[(qd * 4 + r) * SA + t * 16 + ln] = fmaxf(accB[r], 0.f);
            }
        }

        // ---- d2: D = relu(Y) @ Wd2 (single bf16) ----
        {
            bf16x8 a0A, a1A, a0B, a1B;
#pragma unroll
            for (int j = 0; j < 8; ++j) a0A[j] = (short)f2bf(A0[ln * SA + qd * 8 + j]);
#pragma unroll
            for (int j = 0; j < 8; ++j) a1A[j] = (short)f2bf(A0[ln * SA + 32 + qd * 8 + j]);
#pragma unroll
            for (int j = 0; j < 8; ++j) a0B[j] = (short)f2bf(A1[ln * SA + qd * 8 + j]);
#pragma unroll
            for (int j = 0; j < 8; ++j) a1B[j] = (short)f2bf(A1[ln * SA + 32 + qd * 8 + j]);
            const bf16x8 b0 = *(const bf16x8*)&wsm[OW2 + ln * SW + qd * 8];
            const bf16x8 b1 = *(const bf16x8*)&wsm[OW2 + ln * SW + 32 + qd * 8];
            const float bv = bd2v;
            f32x4 accA = {bv, bv, bv, bv};
            f32x4 accB = {bv, bv, bv, bv};
            accA = __builtin_amdgcn_mfma_f32_16x16x32_bf16(a0A, b0, accA, 0, 0, 0);
            accA = __builtin_amdgcn_mfma_f32_16x16x32_bf16(a1A, b1, accA, 0, 0, 0);
            accB = __builtin_amdgcn_mfma_f32_16x16x32_bf16(a0B, b0, accB, 0, 0, 0);
            accB = __builtin_amdgcn_mfma_f32_16x16x32_bf16(a1B, b1, accB, 0, 0, 0);
            if (ln == 15) {
#pragma unroll
                for (int r = 0; r < 4; ++r) {
                    out[3 * n + pt_base + qd * 4 + r]      = fmaxf(accA[r], 0.f);
                    out[3 * n + pt_base + 16 + qd * 4 + r] = fmaxf(accB[r], 0.f);
                }
            }
#pragma unroll
            for (int r = 0; r < 4; ++r) {
                A0[(qd * 4 + r) * SA + ln] = accA[r];
                A1[(qd * 4 + r) * SA + ln] = accB[r];
            }
        }

        // ---- SH -> act fp32, k=16..40, per point ----
        SH_EMIT(&A0[ln * SA + 16], dAx, dAy, dAz)
        SH_EMIT(&A1[ln * SA + 16], dBx, dBy, dBz)

        // ---- c1: H1 = [D|SH|0] @ Wc1 (split), shared B ----
        {
            bf16x8 hA0, hA1, lA0, lA1, hB0, hB1, lB0, lB1;
            LOAD_SPLITP(A0, hA0, lA0, qd * 8)
            LOAD_SPLITP(A0, hA1, lA1, 32 + qd * 8)
            LOAD_SPLITP(A1, hB0, lB0, qd * 8)
            LOAD_SPLITP(A1, hB1, lB1, 32 + qd * 8)
#pragma unroll
            for (int t = 0; t < 4; ++t) {
                const float bv = bc1v[t];
                f32x4 accA = {bv, bv, bv, bv};
                f32x4 accB = {bv, bv, bv, bv};
                SPLIT_TILE2(accA, accB, hA0, hA1, lA0, lA1, hB0, hB1, lB0, lB1, OC1H, OC1L, t * 16 + ln)
#pragma unroll
                for (int r = 0; r < 4; ++r) {
                    A0[(qd * 4 + r) * SA + t * 16 + ln] = fmaxf(accA[r], 0.f);
                    A1[(qd * 4 + r) * SA + t * 16 + ln] = fmaxf(accB[r], 0.f);
                }
            }
        }

        // ---- c2: H2 = relu(H1) @ Wc2 (split), shared B ----
        {
            bf16x8 hA0, hA1, lA0, lA1, hB0, hB1, lB0, lB1;
            LOAD_SPLITP(A0, hA0, lA0, qd * 8)
            LOAD_SPLITP(A0, hA1, lA1, 32 + qd * 8)
            LOAD_SPLITP(A1, hB0, lB0, qd * 8)
            LOAD_SPLITP(A1, hB1, lB1, 32 + qd * 8)
#pragma unroll
            for (int t = 0; t < 4; ++t) {
                const float bv = bc2v[t];
                f32x4 accA = {bv, bv, bv, bv};
                f32x4 accB = {bv, bv, bv, bv};
                SPLIT_TILE2(accA, accB, hA0, hA1, lA0, lA1, hB0, hB1, lB0, lB1, OC2H, OC2L, t * 16 + ln)
#pragma unroll
                for (int r = 0; r < 4; ++r) {
                    A0[(qd * 4 + r) * SA + t * 16 + ln] = fmaxf(accA[r], 0.f);
                    A1[(qd * 4 + r) * SA + t * 16 + ln] = fmaxf(accB[r], 0.f);
                }
            }
        }

        // ---- c3 + sigmoid, shared B (rows 0-2 real, row 3 zero) ----
        {
            bf16x8 hA0, hA1, lA0, lA1, hB0, hB1, lB0, lB1;
            LOAD_SPLITP(A0, hA0, lA0, qd * 8)
            LOAD_SPLITP(A0, hA1, lA1, 32 + qd * 8)
            LOAD_SPLITP(A1, hB0, lB0, qd * 8)
            LOAD_SPLITP(A1, hB1, lB1, 32 + qd * 8)
            const float bv = bc3v;
            f32x4 accA = {bv, bv, bv, bv};
            f32x4 accB = {bv, bv, bv, bv};
            SPLIT_TILE2(accA, accB, hA0, hA1, lA0, lA1, hB0, hB1, lB0, lB1, OC3H, OC3L, (ln & 3))
            if (ln < 3) {
#pragma unroll
                for (int r = 0; r < 4; ++r) {
                    out[3 * (pt_base + qd * 4 + r) + ln]      = 1.f / (1.f + expf(-accA[r]));
                    out[3 * (pt_base + 16 + qd * 4 + r) + ln] = 1.f / (1.f + expf(-accB[r]));
                }
            }
        }
    }
}

// ------------------------------------------------------------------
// Fallback: round-1 fused kernel (if ws too small / n not 2^19) — proven
// ------------------------------------------------------------------
__global__ __launch_bounds__(256)
void nerf_fused(const float* __restrict__ pos,
                const float* __restrict__ dirp,
                const float* __restrict__ tables,
                const float* __restrict__ Wd1, const float* __restrict__ bd1,
                const float* __restrict__ Wd2, const float* __restrict__ bd2,
                const float* __restrict__ Wc1, const float* __restrict__ bc1,
                const float* __restrict__ Wc2, const float* __restrict__ bc2,
                const float* __restrict__ Wc3, const float* __restrict__ bc3,
                float* __restrict__ out, int n)
{
    const int idx = blockIdx.x * blockDim.x + threadIdx.x;
    if (idx >= n) return;
    const float px = pos[3 * idx + 0], py = pos[3 * idx + 1], pz = pos[3 * idx + 2];
    float y[64];
#pragma unroll
    for (int j = 0; j < 64; ++j) y[j] = bd1[j];
#pragma unroll
    for (int l = 0; l < LEVELS; ++l) {
        const float resf = (float)(16 << l);
        const float tx = px * resf, ty = py * resf, tz = pz * resf;
        const float fx = floorf(tx), fy = floorf(ty), fz = floorf(tz);
        const float wx = tx - fx, wy = ty - fy, wz = tz - fz;
        const unsigned ix = (unsigned)(int)fx, iy = (unsigned)(int)fy, iz = (unsigned)(int)fz;
        const unsigned hy0 = iy * 2654435761u, hy1 = hy0 + 2654435761u;
        const unsigned hz0 = iz * 805459861u,  hz1 = hz0 + 805459861u;
        const unsigned ix1 = ix + 1u;
        const float2* tb = (const float2*)tables + (size_t)l * TBL;
        const float2 e000 = tb[(ix  ^ hy0 ^ hz0) & TMASK];
        const float2 e001 = tb[(ix  ^ hy0 ^ hz1) & TMASK];
        const float2 e010 = tb[(ix  ^ hy1 ^ hz0) & TMASK];
        const float2 e011 = tb[(ix  ^ hy1 ^ hz1) & TMASK];
        const float2 e100 = tb[(ix1 ^ hy0 ^ hz0) & TMASK];
        const float2 e101 = tb[(ix1 ^ hy0 ^ hz1) & TMASK];
        const float2 e110 = tb[(ix1 ^ hy1 ^ hz0) & TMASK];
        const float2 e111 = tb[(ix1 ^ hy1 ^ hz1) & TMASK];
        const float ux = 1.f - wx, uy = 1.f - wy, uz = 1.f - wz;
        const float c000 = ux*uy*uz, c001 = ux*uy*wz, c010 = ux*wy*uz, c011 = ux*wy*wz;
        const float c100 = wx*uy*uz, c101 = wx*uy*wz, c110 = wx*wy*uz, c111 = wx*wy*wz;
        float f0 = e000.x*c000, f1 = e000.y*c000;
        f0 = fmaf(e001.x,c001,f0); f1 = fmaf(e001.y,c001,f1);
        f0 = fmaf(e010.x,c010,f0); f1 = fmaf(e010.y,c010,f1);
        f0 = fmaf(e011.x,c011,f0); f1 = fmaf(e011.y,c011,f1);
        f0 = fmaf(e100.x,c100,f0); f1 = fmaf(e100.y,c100,f1);
        f0 = fmaf(e101.x,c101,f0); f1 = fmaf(e101.y,c101,f1);
        f0 = fmaf(e110.x,c110,f0); f1 = fmaf(e110.y,c110,f1);
        f0 = fmaf(e111.x,c111,f0); f1 = fmaf(e111.y,c111,f1);
        const float* w0 = Wd1 + (size_t)(2 * l) * 64;
#pragma unroll
        for (int j = 0; j < 64; ++j)
            y[j] = fmaf(f0, w0[j], fmaf(f1, w0[64 + j], y[j]));
    }
    float d[16];
#pragma unroll
    for (int k = 0; k < 16; ++k) d[k] = bd2[k];
#pragma unroll
    for (int j = 0; j < 64; ++j) {
        const float a = fmaxf(y[j], 0.f);
#pragma unroll
        for (int k = 0; k < 16; ++k) d[k] = fmaf(a, Wd2[j * 16 + k], d[k]);
    }
    out[3 * n + idx] = fmaxf(d[15], 0.f);
    const float dx = dirp[3*idx], dy = dirp[3*idx+1], dz = dirp[3*idx+2];
    float sh[25];
    SH_BLOCK(sh, dx, dy, dz)
    float h1[64];
#pragma unroll
    for (int j = 0; j < 64; ++j) h1[j] = bc1[j];
#pragma unroll
    for (int i = 0; i < 16; ++i) {
#pragma unroll
        for (int j = 0; j < 64; ++j) h1[j] = fmaf(d[i], Wc1[i * 64 + j], h1[j]);
    }
#pragma unroll
    for (int s = 0; s < 25; ++s) {
#pragma unroll
        for (int j = 0; j < 64; ++j) h1[j] = fmaf(sh[s], Wc1[(16 + s) * 64 + j], h1[j]);
    }
    float h2[64];
#pragma unroll
    for (int j = 0; j < 64; ++j) h2[j] = bc2[j];
#pragma unroll
    for (int i = 0; i < 64; ++i) {
        const float a = fmaxf(h1[i], 0.f);
#pragma unroll
        for (int j = 0; j < 64; ++j) h2[j] = fmaf(a, Wc2[i * 64 + j], h2[j]);
    }
    float r0 = bc3[0], r1 = bc3[1], r2 = bc3[2];
#pragma unroll
    for (int j = 0; j < 64; ++j) {
        const float a = fmaxf(h2[j], 0.f);
        r0 = fmaf(a, Wc3[j * 3 + 0], r0);
        r1 = fmaf(a, Wc3[j * 3 + 1], r1);
        r2 = fmaf(a, Wc3[j * 3 + 2], r2);
    }
    out[3 * idx + 0] = 1.f / (1.f + expf(-r0));
    out[3 * idx + 1] = 1.f / (1.f + expf(-r1));
    out[3 * idx + 2] = 1.f / (1.f + expf(-r2));
}

extern "C" void kernel_launch(void* const* d_in, const int* in_sizes, int n_in,
                              void* d_out, int out_size, void* d_ws, size_t ws_size,
                              hipStream_t stream) {
    const float* pos    = (const float*)d_in[0];
    const float* dir    = (const float*)d_in[1];
    const float* tables = (const float*)d_in[2];
    const float* Wd1 = (const float*)d_in[3];
    const float* bd1 = (const float*)d_in[4];
    const float* Wd2 = (const float*)d_in[5];
    const float* bd2 = (const float*)d_in[6];
    const float* Wc1 = (const float*)d_in[7];
    const float* bc1 = (const float*)d_in[8];
    const float* Wc2 = (const float*)d_in[9];
    const float* bc2 = (const float*)d_in[10];
    const float* Wc3 = (const float*)d_in[11];
    const float* bc3 = (const float*)d_in[12];

    const int n = in_sizes[0] / 3;
    const int blocks = (n + 255) / 256;

    // workspace layout: [0, n*64) packed-bf16 feature planes;
    //                   [n*64, n*128) packed-bf16 tables (16*TBL uints)
    if (ws_size >= (size_t)n * 128 && n == 524288) {
        unsigned int* wsp  = (unsigned int*)d_ws;
        unsigned int* tb16 = (unsigned int*)((char*)d_ws + (size_t)n * 64);
        const int total = LEVELS * TBL;
        cvt_tables<<<total / 1024, 256, 0, stream>>>(tables, tb16, total);
        ngp_encode_lvl<<<8 * blocks, 256, 0, stream>>>(pos, tb16, wsp, n, 0);
        ngp_encode_lvl<<<8 * blocks, 256, 0, stream>>>(pos, tb16, wsp, n, 8);
        ngp_mlp_mfma4<<<n / (GROUPS * 128), 256, 0, stream>>>((const unsigned int*)wsp, dir,
                                                              Wd1, bd1, Wd2, bd2,
                                                              Wc1, bc1, Wc2, bc2, Wc3, bc3,
                                                              (float*)d_out, n);
    } else {
        nerf_fused<<<blocks, 256, 0, stream>>>(pos, dir, tables,
                                               Wd1, bd1, Wd2, bd2,
                                               Wc1, bc1, Wc2, bc2, Wc3, bc3,
                                               (float*)d_out, n);
    }
}

// Round 11
// 349.939 us; speedup vs baseline: 1.2291x; 1.0082x over previous
//
#include <hip/hip_runtime.h>
#include <math.h>

#define LEVELS 16
#define TBL 524288          // 2^19 entries per level
#define TMASK (TBL - 1)

typedef short bf16x8 __attribute__((ext_vector_type(8)));
typedef float f32x4  __attribute__((ext_vector_type(4)));
typedef float fvec4  __attribute__((ext_vector_type(4)));
typedef unsigned int uvec4 __attribute__((ext_vector_type(4)));

static __device__ __forceinline__ unsigned short f2bf(float x) {
    unsigned u = __float_as_uint(x);
    u += 0x7fffu + ((u >> 16) & 1u);    // RNE
    return (unsigned short)(u >> 16);
}
static __device__ __forceinline__ float b2f(unsigned short h) {
    return __uint_as_float(((unsigned)h) << 16);
}

// SH degree-4 block, constants computed exactly as round-1 (verified correct).
#define SH_BLOCK(sh, dx, dy, dz)                                                          \
    const float x2 = dx * dx, y2 = dy * dy, z2 = dz * dz;                                 \
    const float xy = dx * dy, xz = dx * dz, yz = dy * dz;                                 \
    const float x4 = x2 * x2, y4 = y2 * y2;                                               \
    const float c0  = (float)(0.5 * sqrt(1.0 / M_PI));                                    \
    const float c1  = (float)(0.5 * sqrt(3.0 / M_PI));                                    \
    const float sub = (float)(0.25 * sqrt(5.0 / M_PI));                                   \
    const float v1  = (float)(0.25 * sqrt(15.0 / M_PI));                                  \
    const float v2  = (float)(0.5 * sqrt(15.0 / M_PI));                                   \
    const float v3  = (float)(0.75 * sqrt(5.0 / M_PI));                                   \
    const float w1c = (float)(0.25 * sqrt(105.0 / M_PI));                                 \
    const float w2c = (float)(0.5 * sqrt(105.0 / M_PI));                                  \
    const float w3c = (float)(0.25 * sqrt(35.0 / (2.0 * M_PI)));                          \
    const float w4c = (float)(0.5 * sqrt(7.0 / (6.0 * M_PI)));                            \
    sh[0] = c0;                                                                           \
    sh[1] = -c1 * dy;                                                                     \
    sh[2] =  c1 * dz;                                                                     \
    sh[3] = -c1 * dx;                                                                     \
    sh[4] =  v2 * xy;                                                                     \
    sh[5] = -v2 * yz;                                                                     \
    sh[6] =  v3 * z2 - sub;                                                               \
    sh[7] = -v2 * xz;                                                                     \
    sh[8] =  v1 * x2 - v1 * y2;                                                           \
    sh[9]  = -w3c * dy * (3.0f * x2 - y2);                                                \
    sh[10] =  w2c * xy * dz;                                                              \
    sh[11] =  w4c * dy * (1.5f - 7.5f * z2);                                              \
    sh[12] =  1.24392110863372f * dz * (1.5f * z2 - 0.5f) - 0.497568443453487f * dz;      \
    sh[13] =  w4c * dx * (1.5f - 7.5f * z2);                                              \
    sh[14] =  w1c * dz * (x2 - y2);                                                       \
    sh[15] = -w3c * dx * (x2 - 3.0f * y2);                                                \
    sh[16] =  2.5033429417967f * xy * (x2 - y2);                                          \
    sh[17] = -1.77013076977993f * yz * (3.0f * x2 - y2);                                  \
    sh[18] =  0.126156626101008f * xy * (52.5f * z2 - 7.5f);                              \
    sh[19] =  0.267618617422916f * dy * (2.33333333333333f * dz * (1.5f - 7.5f * z2) + 4.0f * dz); \
    sh[20] =  1.48099765681286f * dz * (1.66666666666667f * dz * (1.5f * z2 - 0.5f) - 0.666666666666667f * dz) \
              - 0.952069922236839f * z2 + 0.317356640745613f;                             \
    sh[21] =  0.267618617422916f * dx * (2.33333333333333f * dz * (1.5f - 7.5f * z2) + 4.0f * dz); \
    sh[22] =  0.063078313050504f * (x2 - y2) * (52.5f * z2 - 7.5f);                       \
    sh[23] = -1.77013076977993f * xz * (x2 - 3.0f * y2);                                  \
    sh[24] = -3.75501441269506f * x2 * y2 + 0.625835735449176f * x4 + 0.625835735449176f * y4;

// Per-point SH emit into an act row pointer, predicated by qd (bit-identical exprs).
#define SH_EMIT(Ash, DXV, DYV, DZV)                                                        \
    {                                                                                      \
        const float sx2 = (DXV)*(DXV), sy2 = (DYV)*(DYV), sz2 = (DZV)*(DZV);               \
        const float sxy = (DXV)*(DYV), sxz = (DXV)*(DZV), syz = (DYV)*(DZV);               \
        const float sx4 = sx2*sx2, sy4 = sy2*sy2;                                          \
        const float k0  = (float)(0.5 * sqrt(1.0 / M_PI));                                 \
        const float k1  = (float)(0.5 * sqrt(3.0 / M_PI));                                 \
        const float ksub= (float)(0.25 * sqrt(5.0 / M_PI));                                \
        const float kv1 = (float)(0.25 * sqrt(15.0 / M_PI));                               \
        const float kv2 = (float)(0.5 * sqrt(15.0 / M_PI));                                \
        const float kv3 = (float)(0.75 * sqrt(5.0 / M_PI));                                \
        const float kw1 = (float)(0.25 * sqrt(105.0 / M_PI));                              \
        const float kw2 = (float)(0.5 * sqrt(105.0 / M_PI));                               \
        const float kw3 = (float)(0.25 * sqrt(35.0 / (2.0 * M_PI)));                       \
        const float kw4 = (float)(0.5 * sqrt(7.0 / (6.0 * M_PI)));                         \
        if ((0  & 3) == qd) (Ash)[0]  = k0;                                                \
        if ((1  & 3) == qd) (Ash)[1]  = -k1 * (DYV);                                       \
        if ((2  & 3) == qd) (Ash)[2]  =  k1 * (DZV);                                       \
        if ((3  & 3) == qd) (Ash)[3]  = -k1 * (DXV);                                       \
        if ((4  & 3) == qd) (Ash)[4]  =  kv2 * sxy;                                        \
        if ((5  & 3) == qd) (Ash)[5]  = -kv2 * syz;                                        \
        if ((6  & 3) == qd) (Ash)[6]  =  kv3 * sz2 - ksub;                                 \
        if ((7  & 3) == qd) (Ash)[7]  = -kv2 * sxz;                                        \
        if ((8  & 3) == qd) (Ash)[8]  =  kv1 * sx2 - kv1 * sy2;                            \
        if ((9  & 3) == qd) (Ash)[9]  = -kw3 * (DYV) * (3.0f * sx2 - sy2);                 \
        if ((10 & 3) == qd) (Ash)[10] =  kw2 * sxy * (DZV);                                \
        if ((11 & 3) == qd) (Ash)[11] =  kw4 * (DYV) * (1.5f - 7.5f * sz2);                \
        if ((12 & 3) == qd) (Ash)[12] =  1.24392110863372f * (DZV) * (1.5f * sz2 - 0.5f) - 0.497568443453487f * (DZV); \
        if ((13 & 3) == qd) (Ash)[13] =  kw4 * (DXV) * (1.5f - 7.5f * sz2);                \
        if ((14 & 3) == qd) (Ash)[14] =  kw1 * (DZV) * (sx2 - sy2);                        \
        if ((15 & 3) == qd) (Ash)[15] = -kw3 * (DXV) * (sx2 - 3.0f * sy2);                 \
        if ((16 & 3) == qd) (Ash)[16] =  2.5033429417967f * sxy * (sx2 - sy2);             \
        if ((17 & 3) == qd) (Ash)[17] = -1.77013076977993f * syz * (3.0f * sx2 - sy2);     \
        if ((18 & 3) == qd) (Ash)[18] =  0.126156626101008f * sxy * (52.5f * sz2 - 7.5f);  \
        if ((19 & 3) == qd) (Ash)[19] =  0.267618617422916f * (DYV) * (2.33333333333333f * (DZV) * (1.5f - 7.5f * sz2) + 4.0f * (DZV)); \
        if ((20 & 3) == qd) (Ash)[20] =  1.48099765681286f * (DZV) * (1.66666666666667f * (DZV) * (1.5f * sz2 - 0.5f) - 0.666666666666667f * (DZV)) \
                                         - 0.952069922236839f * sz2 + 0.317356640745613f;  \
        if ((21 & 3) == qd) (Ash)[21] =  0.267618617422916f * (DXV) * (2.33333333333333f * (DZV) * (1.5f - 7.5f * sz2) + 4.0f * (DZV)); \
        if ((22 & 3) == qd) (Ash)[22] =  0.063078313050504f * (sx2 - sy2) * (52.5f * sz2 - 7.5f); \
        if ((23 & 3) == qd) (Ash)[23] = -1.77013076977993f * sxz * (sx2 - 3.0f * sy2);     \
        if ((24 & 3) == qd) (Ash)[24] = -3.75501441269506f * sx2 * sy2 + 0.625835735449176f * sx4 + 0.625835735449176f * sy4; \
    }

// ------------------------------------------------------------------
// Kernel 0: pack fp32 tables -> bf16x2 (one uint per entry).
// ------------------------------------------------------------------
__global__ __launch_bounds__(256)
void cvt_tables(const float* __restrict__ tables,
                unsigned int* __restrict__ tb16, int total)
{
    const int i = (blockIdx.x * 256 + threadIdx.x) * 4;   // 4 entries/thread
    if (i >= total) return;
    const fvec4 a = __builtin_nontemporal_load((const fvec4*)(tables + 2 * (size_t)i));
    const fvec4 b = __builtin_nontemporal_load((const fvec4*)(tables + 2 * (size_t)i) + 1);
    uvec4 o;
    o.x = ((unsigned)f2bf(a.y) << 16) | f2bf(a.x);
    o.y = ((unsigned)f2bf(a.w) << 16) | f2bf(a.z);
    o.z = ((unsigned)f2bf(b.y) << 16) | f2bf(b.x);
    o.w = ((unsigned)f2bf(b.w) << 16) | f2bf(b.z);
    __builtin_nontemporal_store(o, (uvec4*)&tb16[i]);
}

// ------------------------------------------------------------------
// Kernel 1 (R21): hash-grid gather, single dispatch, R7 level<->XCD
// mapping (l = 2*(b&7) + (b>>14): two 2 MB tables per XCD L2). At
// the L2-request wall (~19 req/cyc/XCD, model 164 us vs meas 157).
// ------------------------------------------------------------------
__global__ __launch_bounds__(256)
void ngp_encode_lvl(const float* __restrict__ pos,
                    const unsigned int* __restrict__ tb16,
                    unsigned int* __restrict__ wsp, int n)
{
    const int b = blockIdx.x;
    const int p = b & 7;
    const int h = b >> 14;                 // 16384 blocks per half (n = 2^19)
    const int l = 2 * p + h;
    const int c = (b & 16383) >> 3;
    const int idx = c * 256 + threadIdx.x;
    if (idx >= n || l >= LEVELS) return;

    const float px = pos[3 * idx + 0];
    const float py = pos[3 * idx + 1];
    const float pz = pos[3 * idx + 2];

    const float resf = (float)(16 << l);
    const float tx = px * resf, ty = py * resf, tz = pz * resf;
    const float fx = floorf(tx), fy = floorf(ty), fz = floorf(tz);
    const float wx = tx - fx, wy = ty - fy, wz = tz - fz;
    const unsigned ix = (unsigned)(int)fx;
    const unsigned iy = (unsigned)(int)fy;
    const unsigned iz = (unsigned)(int)fz;
    const unsigned hy0 = iy * 2654435761u, hy1 = hy0 + 2654435761u;
    const unsigned hz0 = iz * 805459861u,  hz1 = hz0 + 805459861u;
    const unsigned ix1 = ix + 1u;

    const unsigned int* tb = tb16 + (size_t)l * TBL;
    const unsigned hA = hy0 ^ hz0;        // (y=0,z=0)
    const unsigned hB = hy0 ^ hz1;        // (y=0,z=1)
    const unsigned hC = hy1 ^ hz0;        // (y=1,z=0)
    const unsigned hD = hy1 ^ hz1;        // (y=1,z=1)

    unsigned eA0, eA1, eB0, eB1, eC0, eC1, eD0, eD1;   // e{combo}{x}
    if ((ix & 1u) == 0u) {
        // even ix: {ix^h, (ix+1)^h} = {m, m^1} -> one aligned 8B load
        const uint2 pA = *(const uint2*)&tb[((ix ^ hA) & TMASK) & ~1u];
        const uint2 pB = *(const uint2*)&tb[((ix ^ hB) & TMASK) & ~1u];
        const uint2 pC = *(const uint2*)&tb[((ix ^ hC) & TMASK) & ~1u];
        const uint2 pD = *(const uint2*)&tb[((ix ^ hD) & TMASK) & ~1u];
        const unsigned sA = hA & 1u, sB = hB & 1u, sC = hC & 1u, sD = hD & 1u;
        eA0 = sA ? pA.y : pA.x;  eA1 = sA ? pA.x : pA.y;
        eB0 = sB ? pB.y : pB.x;  eB1 = sB ? pB.x : pB.y;
        eC0 = sC ? pC.y : pC.x;  eC1 = sC ? pC.x : pC.y;
        eD0 = sD ? pD.y : pD.x;  eD1 = sD ? pD.x : pD.y;
    } else {
        eA0 = tb[(ix  ^ hA) & TMASK];  eA1 = tb[(ix1 ^ hA) & TMASK];
        eB0 = tb[(ix  ^ hB) & TMASK];  eB1 = tb[(ix1 ^ hB) & TMASK];
        eC0 = tb[(ix  ^ hC) & TMASK];  eC1 = tb[(ix1 ^ hC) & TMASK];
        eD0 = tb[(ix  ^ hD) & TMASK];  eD1 = tb[(ix1 ^ hD) & TMASK];
    }

#define UNPX(e) __uint_as_float((e) << 16)
#define UNPY(e) __uint_as_float((e) & 0xffff0000u)

    const float ux = 1.f - wx, uy = 1.f - wy, uz = 1.f - wz;
    const float c000 = ux * uy * uz, c001 = ux * uy * wz;
    const float c010 = ux * wy * uz, c011 = ux * wy * wz;
    const float c100 = wx * uy * uz, c101 = wx * uy * wz;
    const float c110 = wx * wy * uz, c111 = wx * wy * wz;

    float f0 = UNPX(eA0) * c000, f1 = UNPY(eA0) * c000;
    f0 = fmaf(UNPX(eB0), c001, f0); f1 = fmaf(UNPY(eB0), c001, f1);
    f0 = fmaf(UNPX(eC0), c010, f0); f1 = fmaf(UNPY(eC0), c010, f1);
    f0 = fmaf(UNPX(eD0), c011, f0); f1 = fmaf(UNPY(eD0), c011, f1);
    f0 = fmaf(UNPX(eA1), c100, f0); f1 = fmaf(UNPY(eA1), c100, f1);
    f0 = fmaf(UNPX(eB1), c101, f0); f1 = fmaf(UNPY(eB1), c101, f1);
    f0 = fmaf(UNPX(eC1), c110, f0); f1 = fmaf(UNPY(eC1), c110, f1);
    f0 = fmaf(UNPX(eD1), c111, f0); f1 = fmaf(UNPY(eD1), c111, f1);

    const unsigned int h0 = f2bf(f0);
    const unsigned int h1 = f2bf(f1);
    __builtin_nontemporal_store((h1 << 16) | h0, &wsp[(size_t)l * n + idx]);
}

// ------------------------------------------------------------------
// Kernel 2 (R21): split-precision MFMA MLP, 32 pts/wave-iter.
// R21: SW1 32 -> 40 (Wd1 stride 64 -> 80 B). At 64 B stride, d1's
// B-reads had lanes ln, ln+2 on identical banks with distinct
// addresses = 8-way conflict (2.94x per m136); 80 B gives 2-way
// (free). +1 KB LDS -> 80,256 B/block, x2 = 160.5 KB <= 160 KiB: 2
// blocks/CU preserved. Everything else identical to R20.
// ------------------------------------------------------------------
#define GROUPS 8
#define SW1  40                  // Wd1 k-stride (shorts): 80 B rows, 16B-aligned, 2-way banks
#define SW   72                  // 64-k weight stride (shorts), rows 16B-aligned
#define SA   68                  // act k-stride (floats); 272B rows, 16B-aligned
#define OW1  0                   // 64*40 = 2560
#define OW2  2560                // 16*72 = 1152
#define OC1H 3712                // 64*72 = 4608
#define OC1L 8320
#define OC2H 12928
#define OC2L 17536
#define OC3H 22144               // 4*72 = 288 (rows 0-2 real, row 3 zero)
#define OC3L 22432
#define WTOT 22720               // shorts = 45,440 B; + act 34,816 B = 80,256 B

__global__ __launch_bounds__(256, 2)
void ngp_mlp_mfma4(const unsigned int* __restrict__ wsp,
                   const float* __restrict__ dirp,
                   const float* __restrict__ Wd1, const float* __restrict__ bd1,
                   const float* __restrict__ Wd2, const float* __restrict__ bd2,
                   const float* __restrict__ Wc1, const float* __restrict__ bc1,
                   const float* __restrict__ Wc2, const float* __restrict__ bc2,
                   const float* __restrict__ Wc3, const float* __restrict__ bc3,
                   float* __restrict__ out, int n)
{
    __shared__ short wsm[WTOT];
    __shared__ float act[4 * 32 * SA];     // 34,816 B
    const int tid = threadIdx.x;

    for (int t = tid; t < WTOT; t += 256) wsm[t] = 0;
    __syncthreads();

    for (int g = tid; g < 32 * 64; g += 256) {            // Wd1 (32,64) single
        const int k = g >> 6, nn = g & 63;
        wsm[OW1 + nn * SW1 + k] = f2bf(Wd1[g]);
    }
    for (int g = tid; g < 64 * 16; g += 256) {            // Wd2 (64,16) single
        const int k = g >> 4, nn = g & 15;
        wsm[OW2 + nn * SW + k] = f2bf(Wd2[g]);
    }
    for (int g = tid; g < 41 * 64; g += 256) {            // Wc1 (41,64) hi+lo
        const int k = g >> 6, nn = g & 63;
        const float w = Wc1[g];
        const unsigned short hh = f2bf(w);
        wsm[OC1H + nn * SW + k] = hh;
        wsm[OC1L + nn * SW + k] = f2bf(w - b2f(hh));
    }
    for (int g = tid; g < 64 * 64; g += 256) {            // Wc2 (64,64) hi+lo
        const int k = g >> 6, nn = g & 63;
        const float w = Wc2[g];
        const unsigned short hh = f2bf(w);
        wsm[OC2H + nn * SW + k] = hh;
        wsm[OC2L + nn * SW + k] = f2bf(w - b2f(hh));
    }
    for (int g = tid; g < 64 * 3; g += 256) {             // Wc3 (64,3) hi+lo
        const int k = g / 3, nn = g - 3 * k;
        const float w = Wc3[g];
        const unsigned short hh = f2bf(w);
        wsm[OC3H + nn * SW + k] = hh;
        wsm[OC3L + nn * SW + k] = f2bf(w - b2f(hh));
    }
    __syncthreads();

    const int wid = tid >> 6;              // 0..3
    const int lane = tid & 63;
    const int ln = lane & 15;
    const int qd = lane >> 4;
    float* A0 = act + wid * (32 * SA);     // rows 0-15: sub0
    float* A1 = A0 + 16 * SA;              // rows 16-31: sub1

    float bd1v[4], bc1v[4], bc2v[4];
#pragma unroll
    for (int t = 0; t < 4; ++t) {
        bd1v[t] = bd1[t * 16 + ln];
        bc1v[t] = bc1[t * 16 + ln];
        bc2v[t] = bc2[t * 16 + ln];
    }
    const float bd2v = bd2[ln];
    const float bc3v = (ln < 3) ? bc3[ln] : 0.f;

#define LOAD_SPLITP(AP, ah, al, k0)                              \
    {                                                            \
        _Pragma("unroll")                                        \
        for (int j = 0; j < 8; ++j) {                            \
            const float v = (AP)[ln * SA + (k0) + j];            \
            const unsigned short hb = f2bf(v);                   \
            ah[j] = (short)hb;                                   \
            al[j] = (short)f2bf(v - b2f(hb));                    \
        }                                                        \
    }

// B-tiles loaded ONCE, consumed by both point-subsets. Per-point MFMA
// order identical to the proven R7 kernel (bit-identical results).
#define SPLIT_TILE2(accA, accB, hA0, hA1, lA0, lA1, hB0, hB1, lB0, lB1, OH, OL, row)              \
    {                                                                                             \
        const bf16x8 bh0 = *(const bf16x8*)&wsm[(OH) + (row) * SW + qd * 8];                      \
        const bf16x8 bh1 = *(const bf16x8*)&wsm[(OH) + (row) * SW + 32 + qd * 8];                 \
        accA = __builtin_amdgcn_mfma_f32_16x16x32_bf16(hA0, bh0, accA, 0, 0, 0);                  \
        accA = __builtin_amdgcn_mfma_f32_16x16x32_bf16(hA1, bh1, accA, 0, 0, 0);                  \
        accA = __builtin_amdgcn_mfma_f32_16x16x32_bf16(lA0, bh0, accA, 0, 0, 0);                  \
        accA = __builtin_amdgcn_mfma_f32_16x16x32_bf16(lA1, bh1, accA, 0, 0, 0);                  \
        accB = __builtin_amdgcn_mfma_f32_16x16x32_bf16(hB0, bh0, accB, 0, 0, 0);                  \
        accB = __builtin_amdgcn_mfma_f32_16x16x32_bf16(hB1, bh1, accB, 0, 0, 0);                  \
        accB = __builtin_amdgcn_mfma_f32_16x16x32_bf16(lB0, bh0, accB, 0, 0, 0);                  \
        accB = __builtin_amdgcn_mfma_f32_16x16x32_bf16(lB1, bh1, accB, 0, 0, 0);                  \
        const bf16x8 bl0 = *(const bf16x8*)&wsm[(OL) + (row) * SW + qd * 8];                      \
        const bf16x8 bl1 = *(const bf16x8*)&wsm[(OL) + (row) * SW + 32 + qd * 8];                 \
        accA = __builtin_amdgcn_mfma_f32_16x16x32_bf16(hA0, bl0, accA, 0, 0, 0);                  \
        accA = __builtin_amdgcn_mfma_f32_16x16x32_bf16(hA1, bl1, accA, 0, 0, 0);                  \
        accB = __builtin_amdgcn_mfma_f32_16x16x32_bf16(hB0, bl0, accB, 0, 0, 0);                  \
        accB = __builtin_amdgcn_mfma_f32_16x16x32_bf16(hB1, bl1, accB, 0, 0, 0);                  \
    }

    // ---- register prefetch of group 0's globals (both subsets) ----
    const int ptA0 = blockIdx.x * (GROUPS * 128) + wid * 32 + ln;
    unsigned int xuA0, xuA1, xuA2, xuA3, xuB0, xuB1, xuB2, xuB3;
    float dqA0, dqA1, dqA2, dqB0, dqB1, dqB2;
    xuA0 = wsp[(size_t)(qd * 4 + 0) * n + ptA0];
    xuA1 = wsp[(size_t)(qd * 4 + 1) * n + ptA0];
    xuA2 = wsp[(size_t)(qd * 4 + 2) * n + ptA0];
    xuA3 = wsp[(size_t)(qd * 4 + 3) * n + ptA0];
    xuB0 = wsp[(size_t)(qd * 4 + 0) * n + ptA0 + 16];
    xuB1 = wsp[(size_t)(qd * 4 + 1) * n + ptA0 + 16];
    xuB2 = wsp[(size_t)(qd * 4 + 2) * n + ptA0 + 16];
    xuB3 = wsp[(size_t)(qd * 4 + 3) * n + ptA0 + 16];
    dqA0 = dirp[3 * ptA0 + 0];
    dqA1 = dirp[3 * ptA0 + 1];
    dqA2 = dirp[3 * ptA0 + 2];
    dqB0 = dirp[3 * (ptA0 + 16) + 0];
    dqB1 = dirp[3 * (ptA0 + 16) + 1];
    dqB2 = dirp[3 * (ptA0 + 16) + 2];

#pragma unroll 1
    for (int grp = 0; grp < GROUPS; ++grp) {
        const int pt_base = blockIdx.x * (GROUPS * 128) + grp * 128 + wid * 32;
        const int pt = pt_base + ln;

        bf16x8 axA, axB;
        axA[0] = (short)(xuA0 & 0xffffu); axA[1] = (short)(xuA0 >> 16);
        axA[2] = (short)(xuA1 & 0xffffu); axA[3] = (short)(xuA1 >> 16);
        axA[4] = (short)(xuA2 & 0xffffu); axA[5] = (short)(xuA2 >> 16);
        axA[6] = (short)(xuA3 & 0xffffu); axA[7] = (short)(xuA3 >> 16);
        axB[0] = (short)(xuB0 & 0xffffu); axB[1] = (short)(xuB0 >> 16);
        axB[2] = (short)(xuB1 & 0xffffu); axB[3] = (short)(xuB1 >> 16);
        axB[4] = (short)(xuB2 & 0xffffu); axB[5] = (short)(xuB2 >> 16);
        axB[6] = (short)(xuB3 & 0xffffu); axB[7] = (short)(xuB3 >> 16);
        const float dAx = dqA0, dAy = dqA1, dAz = dqA2;
        const float dBx = dqB0, dBy = dqB1, dBz = dqB2;

        if (grp + 1 < GROUPS) {
            const int ptn = pt + 128;
            xuA0 = wsp[(size_t)(qd * 4 + 0) * n + ptn];
            xuA1 = wsp[(size_t)(qd * 4 + 1) * n + ptn];
            xuA2 = wsp[(size_t)(qd * 4 + 2) * n + ptn];
            xuA3 = wsp[(size_t)(qd * 4 + 3) * n + ptn];
            xuB0 = wsp[(size_t)(qd * 4 + 0) * n + ptn + 16];
            xuB1 = wsp[(size_t)(qd * 4 + 1) * n + ptn + 16];
            xuB2 = wsp[(size_t)(qd * 4 + 2) * n + ptn + 16];
            xuB3 = wsp[(size_t)(qd * 4 + 3) * n + ptn + 16];
            dqA0 = dirp[3 * ptn + 0];
            dqA1 = dirp[3 * ptn + 1];
            dqA2 = dirp[3 * ptn + 2];
            dqB0 = dirp[3 * (ptn + 16) + 0];
            dqB1 = dirp[3 * (ptn + 16) + 1];
            dqB2 = dirp[3 * (ptn + 16) + 2];
        }

        // ---- d1: Y = X @ Wd1 (single bf16), both subsets share B ----
#pragma unroll
        for (int t = 0; t < 4; ++t) {
            const bf16x8 b = *(const bf16x8*)&wsm[OW1 + (t * 16 + ln) * SW1 + qd * 8];
            const float bv = bd1v[t];
            f32x4 accA = {bv, bv, bv, bv};
            f32x4 accB = {bv, bv, bv, bv};
            accA = __builtin_amdgcn_mfma_f32_16x16x32_bf16(axA, b, accA, 0, 0, 0);
            accB = __builtin_amdgcn_mfma_f32_16x16x32_bf16(axB, b, accB, 0, 0, 0);
#pragma unroll
            for (int r = 0; r < 4; ++r) {
                A0[(qd * 4 + r) * SA + t * 16 + ln] = fmaxf(accA[r], 0.f);
                A1[(qd * 4 + r) * SA + t * 16 + ln] = fmaxf(accB[r], 0.f);
            }
        }

        // ---- d2: D = relu(Y) @ Wd2 (single bf16) ----
        {
            bf16x8 a0A, a1A, a0B, a1B;
#pragma unroll
            for (int j = 0; j < 8; ++j) a0A[j] = (short)f2bf(A0[ln * SA + qd * 8 + j]);
#pragma unroll
            for (int j = 0; j < 8; ++j) a1A[j] = (short)f2bf(A0[ln * SA + 32 + qd * 8 + j]);
#pragma unroll
            for (int j = 0; j < 8; ++j) a0B[j] = (short)f2bf(A1[ln * SA + qd * 8 + j]);
#pragma unroll
            for (int j = 0; j < 8; ++j) a1B[j] = (short)f2bf(A1[ln * SA + 32 + qd * 8 + j]);
            const bf16x8 b0 = *(const bf16x8*)&wsm[OW2 + ln * SW + qd * 8];
            const bf16x8 b1 = *(const bf16x8*)&wsm[OW2 + ln * SW + 32 + qd * 8];
            const float bv = bd2v;
            f32x4 accA = {bv, bv, bv, bv};
            f32x4 accB = {bv, bv, bv, bv};
            accA = __builtin_amdgcn_mfma_f32_16x16x32_bf16(a0A, b0, accA, 0, 0, 0);
            accA = __builtin_amdgcn_mfma_f32_16x16x32_bf16(a1A, b1, accA, 0, 0, 0);
            accB = __builtin_amdgcn_mfma_f32_16x16x32_bf16(a0B, b0, accB, 0, 0, 0);
            accB = __builtin_amdgcn_mfma_f32_16x16x32_bf16(a1B, b1, accB, 0, 0, 0);
            if (ln == 15) {
#pragma unroll
                for (int r = 0; r < 4; ++r) {
                    out[3 * n + pt_base + qd * 4 + r]      = fmaxf(accA[r], 0.f);
                    out[3 * n + pt_base + 16 + qd * 4 + r] = fmaxf(accB[r], 0.f);
                }
            }
#pragma unroll
            for (int r = 0; r < 4; ++r) {
                A0[(qd * 4 + r) * SA + ln] = accA[r];
                A1[(qd * 4 + r) * SA + ln] = accB[r];
            }
        }

        // ---- SH -> act fp32, k=16..40, per point ----
        SH_EMIT(&A0[ln * SA + 16], dAx, dAy, dAz)
        SH_EMIT(&A1[ln * SA + 16], dBx, dBy, dBz)

        // ---- c1: H1 = [D|SH|0] @ Wc1 (split), shared B ----
        {
            bf16x8 hA0, hA1, lA0, lA1, hB0, hB1, lB0, lB1;
            LOAD_SPLITP(A0, hA0, lA0, qd * 8)
            LOAD_SPLITP(A0, hA1, lA1, 32 + qd * 8)
            LOAD_SPLITP(A1, hB0, lB0, qd * 8)
            LOAD_SPLITP(A1, hB1, lB1, 32 + qd * 8)
#pragma unroll
            for (int t = 0; t < 4; ++t) {
                const float bv = bc1v[t];
                f32x4 accA = {bv, bv, bv, bv};
                f32x4 accB = {bv, bv, bv, bv};
                SPLIT_TILE2(accA, accB, hA0, hA1, lA0, lA1, hB0, hB1, lB0, lB1, OC1H, OC1L, t * 16 + ln)
#pragma unroll
                for (int r = 0; r < 4; ++r) {
                    A0[(qd * 4 + r) * SA + t * 16 + ln] = fmaxf(accA[r], 0.f);
                    A1[(qd * 4 + r) * SA + t * 16 + ln] = fmaxf(accB[r], 0.f);
                }
            }
        }

        // ---- c2: H2 = relu(H1) @ Wc2 (split), shared B ----
        {
            bf16x8 hA0, hA1, lA0, lA1, hB0, hB1, lB0, lB1;
            LOAD_SPLITP(A0, hA0, lA0, qd * 8)
            LOAD_SPLITP(A0, hA1, lA1, 32 + qd * 8)
            LOAD_SPLITP(A1, hB0, lB0, qd * 8)
            LOAD_SPLITP(A1, hB1, lB1, 32 + qd * 8)
#pragma unroll
            for (int t = 0; t < 4; ++t) {
                const float bv = bc2v[t];
                f32x4 accA = {bv, bv, bv, bv};
                f32x4 accB = {bv, bv, bv, bv};
                SPLIT_TILE2(accA, accB, hA0, hA1, lA0, lA1, hB0, hB1, lB0, lB1, OC2H, OC2L, t * 16 + ln)
#pragma unroll
                for (int r = 0; r < 4; ++r) {
                    A0[(qd * 4 + r) * SA + t * 16 + ln] = fmaxf(accA[r], 0.f);
                    A1[(qd * 4 + r) * SA + t * 16 + ln] = fmaxf(accB[r], 0.f);
                }
            }
        }

        // ---- c3 + sigmoid, shared B (rows 0-2 real, row 3 zero) ----
        {
            bf16x8 hA0, hA1, lA0, lA1, hB0, hB1, lB0, lB1;
            LOAD_SPLITP(A0, hA0, lA0, qd * 8)
            LOAD_SPLITP(A0, hA1, lA1, 32 + qd * 8)
            LOAD_SPLITP(A1, hB0, lB0, qd * 8)
            LOAD_SPLITP(A1, hB1, lB1, 32 + qd * 8)
            const float bv = bc3v;
            f32x4 accA = {bv, bv, bv, bv};
            f32x4 accB = {bv, bv, bv, bv};
            SPLIT_TILE2(accA, accB, hA0, hA1, lA0, lA1, hB0, hB1, lB0, lB1, OC3H, OC3L, (ln & 3))
            if (ln < 3) {
#pragma unroll
                for (int r = 0; r < 4; ++r) {
                    out[3 * (pt_base + qd * 4 + r) + ln]      = 1.f / (1.f + expf(-accA[r]));
                    out[3 * (pt_base + 16 + qd * 4 + r) + ln] = 1.f / (1.f + expf(-accB[r]));
                }
            }
        }
    }
}

// ------------------------------------------------------------------
// Fallback: round-1 fused kernel (if ws too small / n not 2^19) — proven
// ------------------------------------------------------------------
__global__ __launch_bounds__(256)
void nerf_fused(const float* __restrict__ pos,
                const float* __restrict__ dirp,
                const float* __restrict__ tables,
                const float* __restrict__ Wd1, const float* __restrict__ bd1,
                const float* __restrict__ Wd2, const float* __restrict__ bd2,
                const float* __restrict__ Wc1, const float* __restrict__ bc1,
                const float* __restrict__ Wc2, const float* __restrict__ bc2,
                const float* __restrict__ Wc3, const float* __restrict__ bc3,
                float* __restrict__ out, int n)
{
    const int idx = blockIdx.x * blockDim.x + threadIdx.x;
    if (idx >= n) return;
    const float px = pos[3 * idx + 0], py = pos[3 * idx + 1], pz = pos[3 * idx + 2];
    float y[64];
#pragma unroll
    for (int j = 0; j < 64; ++j) y[j] = bd1[j];
#pragma unroll
    for (int l = 0; l < LEVELS; ++l) {
        const float resf = (float)(16 << l);
        const float tx = px * resf, ty = py * resf, tz = pz * resf;
        const float fx = floorf(tx), fy = floorf(ty), fz = floorf(tz);
        const float wx = tx - fx, wy = ty - fy, wz = tz - fz;
        const unsigned ix = (unsigned)(int)fx, iy = (unsigned)(int)fy, iz = (unsigned)(int)fz;
        const unsigned hy0 = iy * 2654435761u, hy1 = hy0 + 2654435761u;
        const unsigned hz0 = iz * 805459861u,  hz1 = hz0 + 805459861u;
        const unsigned ix1 = ix + 1u;
        const float2* tb = (const float2*)tables + (size_t)l * TBL;
        const float2 e000 = tb[(ix  ^ hy0 ^ hz0) & TMASK];
        const float2 e001 = tb[(ix  ^ hy0 ^ hz1) & TMASK];
        const float2 e010 = tb[(ix  ^ hy1 ^ hz0) & TMASK];
        const float2 e011 = tb[(ix  ^ hy1 ^ hz1) & TMASK];
        const float2 e100 = tb[(ix1 ^ hy0 ^ hz0) & TMASK];
        const float2 e101 = tb[(ix1 ^ hy0 ^ hz1) & TMASK];
        const float2 e110 = tb[(ix1 ^ hy1 ^ hz0) & TMASK];
        const float2 e111 = tb[(ix1 ^ hy1 ^ hz1) & TMASK];
        const float ux = 1.f - wx, uy = 1.f - wy, uz = 1.f - wz;
        const float c000 = ux*uy*uz, c001 = ux*uy*wz, c010 = ux*wy*uz, c011 = ux*wy*wz;
        const float c100 = wx*uy*uz, c101 = wx*uy*wz, c110 = wx*wy*uz, c111 = wx*wy*wz;
        float f0 = e000.x*c000, f1 = e000.y*c000;
        f0 = fmaf(e001.x,c001,f0); f1 = fmaf(e001.y,c001,f1);
        f0 = fmaf(e010.x,c010,f0); f1 = fmaf(e010.y,c010,f1);
        f0 = fmaf(e011.x,c011,f0); f1 = fmaf(e011.y,c011,f1);
        f0 = fmaf(e100.x,c100,f0); f1 = fmaf(e100.y,c100,f1);
        f0 = fmaf(e101.x,c101,f0); f1 = fmaf(e101.y,c101,f1);
        f0 = fmaf(e110.x,c110,f0); f1 = fmaf(e110.y,c110,f1);
        f0 = fmaf(e111.x,c111,f0); f1 = fmaf(e111.y,c111,f1);
        const float* w0 = Wd1 + (size_t)(2 * l) * 64;
#pragma unroll
        for (int j = 0; j < 64; ++j)
            y[j] = fmaf(f0, w0[j], fmaf(f1, w0[64 + j], y[j]));
    }
    float d[16];
#pragma unroll
    for (int k = 0; k < 16; ++k) d[k] = bd2[k];
#pragma unroll
    for (int j = 0; j < 64; ++j) {
        const float a = fmaxf(y[j], 0.f);
#pragma unroll
        for (int k = 0; k < 16; ++k) d[k] = fmaf(a, Wd2[j * 16 + k], d[k]);
    }
    out[3 * n + idx] = fmaxf(d[15], 0.f);
    const float dx = dirp[3*idx], dy = dirp[3*idx+1], dz = dirp[3*idx+2];
    float sh[25];
    SH_BLOCK(sh, dx, dy, dz)
    float h1[64];
#pragma unroll
    for (int j = 0; j < 64; ++j) h1[j] = bc1[j];
#pragma unroll
    for (int i = 0; i < 16; ++i) {
#pragma unroll
        for (int j = 0; j < 64; ++j) h1[j] = fmaf(d[i], Wc1[i * 64 + j], h1[j]);
    }
#pragma unroll
    for (int s = 0; s < 25; ++s) {
#pragma unroll
        for (int j = 0; j < 64; ++j) h1[j] = fmaf(sh[s], Wc1[(16 + s) * 64 + j], h1[j]);
    }
    float h2[64];
#pragma unroll
    for (int j = 0; j < 64; ++j) h2[j] = bc2[j];
#pragma unroll
    for (int i = 0; i < 64; ++i) {
        const float a = fmaxf(h1[i], 0.f);
#pragma unroll
        for (int j = 0; j < 64; ++j) h2[j] = fmaf(a, Wc2[i * 64 + j], h2[j]);
    }
    float r0 = bc3[0], r1 = bc3[1], r2 = bc3[2];
#pragma unroll
    for (int j = 0; j < 64; ++j) {
        const float a = fmaxf(h2[j], 0.f);
        r0 = fmaf(a, Wc3[j * 3 + 0], r0);
        r1 = fmaf(a, Wc3[j * 3 + 1], r1);
        r2 = fmaf(a, Wc3[j * 3 + 2], r2);
    }
    out[3 * idx + 0] = 1.f / (1.f + expf(-r0));
    out[3 * idx + 1] = 1.f / (1.f + expf(-r1));
    out[3 * idx + 2] = 1.f / (1.f + expf(-r2));
}

extern "C" void kernel_launch(void* const* d_in, const int* in_sizes, int n_in,
                              void* d_out, int out_size, void* d_ws, size_t ws_size,
                              hipStream_t stream) {
    const float* pos    = (const float*)d_in[0];
    const float* dir    = (const float*)d_in[1];
    const float* tables = (const float*)d_in[2];
    const float* Wd1 = (const float*)d_in[3];
    const float* bd1 = (const float*)d_in[4];
    const float* Wd2 = (const float*)d_in[5];
    const float* bd2 = (const float*)d_in[6];
    const float* Wc1 = (const float*)d_in[7];
    const float* bc1 = (const float*)d_in[8];
    const float* Wc2 = (const float*)d_in[9];
    const float* bc2 = (const float*)d_in[10];
    const float* Wc3 = (const float*)d_in[11];
    const float* bc3 = (const float*)d_in[12];

    const int n = in_sizes[0] / 3;
    const int blocks = (n + 255) / 256;

    // workspace layout: [0, n*64) packed-bf16 feature planes;
    //                   [n*64, n*128) packed-bf16 tables (16*TBL uints)
    if (ws_size >= (size_t)n * 128 && n == 524288) {
        unsigned int* wsp  = (unsigned int*)d_ws;
        unsigned int* tb16 = (unsigned int*)((char*)d_ws + (size_t)n * 64);
        const int total = LEVELS * TBL;
        cvt_tables<<<total / 1024, 256, 0, stream>>>(tables, tb16, total);
        ngp_encode_lvl<<<16 * blocks, 256, 0, stream>>>(pos, tb16, wsp, n);
        ngp_mlp_mfma4<<<n / (GROUPS * 128), 256, 0, stream>>>((const unsigned int*)wsp, dir,
                                                              Wd1, bd1, Wd2, bd2,
                                                              Wc1, bc1, Wc2, bc2, Wc3, bc3,
                                                              (float*)d_out, n);
    } else {
        nerf_fused<<<blocks, 256, 0, stream>>>(pos, dir, tables,
                                               Wd1, bd1, Wd2, bd2,
                                               Wc1, bc1, Wc2, bc2, Wc3, bc3,
                                               (float*)d_out, n);
    }
}